// Round 1
// baseline (346.813 us; speedup 1.0000x reference)
//
#include <hip/hip_runtime.h>

typedef float    f4 __attribute__((ext_vector_type(4)));
typedef _Float16 h8 __attribute__((ext_vector_type(8)));
typedef _Float16 h4 __attribute__((ext_vector_type(4)));

#define DEV static __device__ __forceinline__

DEV f4 mfma16(h8 a, h8 b, f4 c) {
  return __builtin_amdgcn_mfma_f32_16x16x32_f16(a, b, c, 0, 0, 0);
}

DEV void gload16(const void* g, void* lds) {
  __builtin_amdgcn_global_load_lds((__attribute__((address_space(1))) void*)g,
                                   (__attribute__((address_space(3))) void*)lds,
                                   16, 0, 0);
}

// ---------------- fp32 -> fp16 conversion (x + packed weights) ----------------
__global__ __launch_bounds__(256) void cvt_all(
    const float* __restrict__ x,  const float* __restrict__ wq,
    const float* __restrict__ wk, const float* __restrict__ wv,
    const float* __restrict__ wo,
    _Float16* __restrict__ xb, _Float16* __restrict__ wqkv, _Float16* __restrict__ wob)
{
  int b = blockIdx.x;
  const float* src; _Float16* dst; int i4;
  if      (b < 8192)  { src = x;  dst = xb;                 i4 = b * 256; }
  else if (b < 9216)  { src = wq; dst = wqkv;               i4 = (b - 8192)  * 256; }
  else if (b < 10240) { src = wk; dst = wqkv + (1u << 20);  i4 = (b - 9216)  * 256; }
  else if (b < 11264) { src = wv; dst = wqkv + (2u << 20);  i4 = (b - 10240) * 256; }
  else                { src = wo; dst = wob;                i4 = (b - 11264) * 256; }
  i4 += threadIdx.x;
  f4 v = ((const f4*)src)[i4];
  h4 o;
  o[0] = (_Float16)v[0]; o[1] = (_Float16)v[1];
  o[2] = (_Float16)v[2]; o[3] = (_Float16)v[3];
  ((h4*)dst)[i4] = o;
}

// ---------------- GEMM: C[M,N] = A[M,K] * Bt[N,K]^T  (m97 structure) ----------
// MODE 0: write fp32 C row-major.
// MODE 1: scatter fp16 into Q/K/V [B,H,S,HD]; Q gets *0.125*log2(e).
template<int MODE>
__global__ __launch_bounds__(256) void gemm_bt(
    const _Float16* __restrict__ A, const _Float16* __restrict__ Bt,
    float* __restrict__ C,
    _Float16* __restrict__ Qo, _Float16* __restrict__ Ko, _Float16* __restrict__ Vo,
    int N, int Ntiles)
{
  __shared__ _Float16 Al[128 * 32];
  __shared__ _Float16 Bl[128 * 32];
  const int K = 1024;
  int bid = blockIdx.x;
  int tm = bid / Ntiles, tn = bid - tm * Ntiles;
  int m0 = tm * 128, n0 = tn * 128;
  int t = threadIdx.x, w = t >> 6, l = t & 63, lo = l & 15, hi = l >> 4;
  int wr = w >> 1, wc = w & 1;

  const _Float16* Ag = A  + (size_t)(m0 + (t >> 2)) * K + (t & 3) * 8;
  const _Float16* Bg = Bt + (size_t)(n0 + (t >> 2)) * K + (t & 3) * 8;
  _Float16* Alw = Al + w * 512;
  _Float16* Blw = Bl + w * 512;

  f4 acc[4][4] = {};

  for (int k0 = 0; k0 < K; k0 += 32) {
    if (k0) __syncthreads();
    gload16(Ag + k0,          Alw);
    gload16(Ag + 64 * K + k0, Alw + 2048);
    gload16(Bg + k0,          Blw);
    gload16(Bg + 64 * K + k0, Blw + 2048);
    __syncthreads();
    h8 a[4], b[4];
    #pragma unroll
    for (int i = 0; i < 4; ++i)
      a[i] = *(const h8*)(Al + (wr * 64 + i * 16 + lo) * 32 + hi * 8);
    #pragma unroll
    for (int i = 0; i < 4; ++i)
      b[i] = *(const h8*)(Bl + (wc * 64 + i * 16 + lo) * 32 + hi * 8);
    #pragma unroll
    for (int mi = 0; mi < 4; ++mi)
      #pragma unroll
      for (int ni = 0; ni < 4; ++ni)
        acc[mi][ni] = mfma16(a[mi], b[ni], acc[mi][ni]);
  }

  #pragma unroll
  for (int mi = 0; mi < 4; ++mi) {
    #pragma unroll
    for (int ni = 0; ni < 4; ++ni) {
      #pragma unroll
      for (int j = 0; j < 4; ++j) {
        int row = m0 + wr * 64 + mi * 16 + hi * 4 + j;
        int col = n0 + wc * 64 + ni * 16 + lo;
        float v = acc[mi][ni][j];
        if (MODE == 0) {
          C[(size_t)row * N + col] = v;
        } else {
          int which = col >> 10;
          int cw = col & 1023;
          int hh = cw >> 6, hd = cw & 63;
          int bb = row >> 11, ss = row & 2047;
          size_t dst = (size_t)(bb * 16 + hh) * 131072 + (size_t)ss * 64 + hd;
          if (which == 0)      Qo[dst] = (_Float16)(v * 0.1803368801111137f); // 1/8 * log2(e)
          else if (which == 1) Ko[dst] = (_Float16)v;
          else                 Vo[dst] = (_Float16)v;
        }
      }
    }
  }
}

// ---------------- causal flash attention, HD=64, S=2048 ----------------------
// grid: bh(64) x qtile(32); 4 waves, 16 q-rows/wave, KVBLK=64.
__global__ __launch_bounds__(256) void attn_kernel(
    const _Float16* __restrict__ Q, const _Float16* __restrict__ Kb,
    const _Float16* __restrict__ Vb, _Float16* __restrict__ O)
{
  __shared__ _Float16 Kl[64 * 64];     // XOR-swizzled 16B chunks within rows
  __shared__ _Float16 Vt[64 * 72];     // transposed V: [hd][kv], padded rows
  __shared__ _Float16 Pl[4][16 * 72];  // per-wave P tile

  int bid = blockIdx.x;
  int bh = bid >> 5, qt = bid & 31;
  int t = threadIdx.x, w = t >> 6, l = t & 63, lo = l & 15, hi = l >> 4;

  const size_t hoff = (size_t)bh * (2048 * 64);
  const _Float16* Qp = Q + hoff + (size_t)(qt * 64 + w * 16 + lo) * 64 + hi * 8;
  h8 qf0 = *(const h8*)(Qp);
  h8 qf1 = *(const h8*)(Qp + 32);

  f4 acc[4] = {};
  float m_run[4], l_run[4];
  #pragma unroll
  for (int j = 0; j < 4; ++j) { m_run[j] = -1e30f; l_run[j] = 0.f; }

  const _Float16* Kg = Kb + hoff;
  const _Float16* Vg = Vb + hoff;
  int rK  = t >> 3, cK = t & 7;          // K staging: row(+i*32), 16B chunk
  int kvV = t & 31, hd0 = (t >> 5) * 8;  // V staging: kv-major for bank spread

  for (int kt = 0; kt <= qt; ++kt) {
    const _Float16* Kt  = Kg + (size_t)kt * 64 * 64;
    const _Float16* Vtg = Vg + (size_t)kt * 64 * 64;
    if (kt) __syncthreads();
    #pragma unroll
    for (int i = 0; i < 2; ++i) {   // K: gload_lds, pre-swizzled source (m173)
      int row = i * 32 + rK;
      gload16(Kt + (size_t)row * 64 + (size_t)((cK ^ (row & 7)) * 8),
              Kl + i * 2048 + w * 512);
    }
    #pragma unroll
    for (int i = 0; i < 2; ++i) {   // V: reg-staged transpose into Vt[hd][kv]
      int kv = i * 32 + kvV;
      h8 vv = *(const h8*)(Vtg + (size_t)kv * 64 + hd0);
      #pragma unroll
      for (int e = 0; e < 8; ++e)
        Vt[(hd0 + e) * 72 + kv] = vv[e];
    }
    __syncthreads();

    // S = Q K^T (exp2 domain, scale folded into Q)
    f4 sc[4] = {};
    #pragma unroll
    for (int nf = 0; nf < 4; ++nf) {
      int row = nf * 16 + lo;
      h8 kf0 = *(const h8*)(Kl + row * 64 + ((0 + hi) ^ (row & 7)) * 8);
      h8 kf1 = *(const h8*)(Kl + row * 64 + ((4 + hi) ^ (row & 7)) * 8);
      sc[nf] = mfma16(qf0, kf0, sc[nf]);
      sc[nf] = mfma16(qf1, kf1, sc[nf]);
    }

    if (kt == qt) {                 // causal mask on the diagonal tile
      #pragma unroll
      for (int nf = 0; nf < 4; ++nf) {
        int kg = nf * 16 + lo;
        #pragma unroll
        for (int j = 0; j < 4; ++j)
          if (kg > w * 16 + hi * 4 + j) sc[nf][j] = -1e30f;
      }
    }

    // online softmax (wave-parallel, width-16 shfl reduce)
    float corr[4];
    #pragma unroll
    for (int j = 0; j < 4; ++j) {
      float mx = fmaxf(fmaxf(sc[0][j], sc[1][j]), fmaxf(sc[2][j], sc[3][j]));
      #pragma unroll
      for (int d = 1; d < 16; d <<= 1)
        mx = fmaxf(mx, __shfl_xor(mx, d, 16));
      float mn = fmaxf(m_run[j], mx);
      corr[j] = exp2f(m_run[j] - mn);
      m_run[j] = mn;
    }

    float psum[4] = {0.f, 0.f, 0.f, 0.f};
    _Float16 pb[4][4];
    #pragma unroll
    for (int nf = 0; nf < 4; ++nf)
      #pragma unroll
      for (int j = 0; j < 4; ++j) {
        float p = exp2f(sc[nf][j] - m_run[j]);
        psum[j] += p;
        pb[nf][j] = (_Float16)p;
      }
    #pragma unroll
    for (int j = 0; j < 4; ++j) {
      float s = psum[j];
      #pragma unroll
      for (int d = 1; d < 16; d <<= 1) s += __shfl_xor(s, d, 16);
      l_run[j] = l_run[j] * corr[j] + s;
    }
    #pragma unroll
    for (int nf = 0; nf < 4; ++nf)
      #pragma unroll
      for (int j = 0; j < 4; ++j)
        acc[nf][j] *= corr[j];

    // P -> per-wave LDS (D-layout -> A-layout transpose)
    _Float16* Pw = &Pl[w][0];
    #pragma unroll
    for (int nf = 0; nf < 4; ++nf)
      #pragma unroll
      for (int j = 0; j < 4; ++j)
        Pw[(hi * 4 + j) * 72 + nf * 16 + lo] = pb[nf][j];

    __builtin_amdgcn_sched_barrier(0);
    asm volatile("s_waitcnt lgkmcnt(0)" ::: "memory");
    __builtin_amdgcn_sched_barrier(0);

    // O += P V
    #pragma unroll
    for (int ks = 0; ks < 2; ++ks) {
      h8 pf = *(const h8*)(Pw + lo * 72 + ks * 32 + hi * 8);
      #pragma unroll
      for (int nf = 0; nf < 4; ++nf) {
        h8 vf = *(const h8*)(Vt + (nf * 16 + lo) * 72 + ks * 32 + hi * 8);
        acc[nf] = mfma16(pf, vf, acc[nf]);
      }
    }
  }

  int bb = bh >> 4, hh = bh & 15;
  #pragma unroll
  for (int j = 0; j < 4; ++j) {
    float inv = 1.0f / l_run[j];
    int q = qt * 64 + w * 16 + hi * 4 + j;
    _Float16* Op = O + ((size_t)(bb * 2048 + q)) * 1024 + hh * 64 + lo;
    #pragma unroll
    for (int nf = 0; nf < 4; ++nf)
      Op[nf * 16] = (_Float16)(acc[nf][j] * inv);
  }
}

extern "C" void kernel_launch(void* const* d_in, const int* in_sizes, int n_in,
                              void* d_out, int out_size, void* d_ws, size_t ws_size,
                              hipStream_t stream)
{
  const float* x  = (const float*)d_in[0];
  const float* wq = (const float*)d_in[1];
  const float* wk = (const float*)d_in[2];
  const float* wv = (const float*)d_in[3];
  const float* wo = (const float*)d_in[4];
  // d_in[5] = causal mask: implemented analytically.

  char* ws = (char*)d_ws;
  _Float16* xb   = (_Float16*)(ws);                  // 16 MB, reused as Ob later
  _Float16* wqkv = (_Float16*)(ws + (16u << 20));    //  6 MB
  _Float16* wob  = (_Float16*)(ws + (22u << 20));    //  2 MB
  _Float16* Qb   = (_Float16*)(ws + (24u << 20));    // 16 MB
  _Float16* Kb   = (_Float16*)(ws + (40u << 20));    // 16 MB
  _Float16* Vb   = (_Float16*)(ws + (56u << 20));    // 16 MB -> total 72 MB
  _Float16* Ob   = xb;                               // xb dead after QKV GEMM

  cvt_all<<<12288, 256, 0, stream>>>(x, wq, wk, wv, wo, xb, wqkv, wob);
  gemm_bt<1><<<64 * 24, 256, 0, stream>>>(xb, wqkv, nullptr, Qb, Kb, Vb, 3072, 24);
  attn_kernel<<<2048, 256, 0, stream>>>(Qb, Kb, Vb, Ob);
  gemm_bt<0><<<64 * 8, 256, 0, stream>>>(Ob, wob, (float*)d_out,
                                         nullptr, nullptr, nullptr, 1024, 8);
}

// Round 2
// 308.727 us; speedup vs baseline: 1.1234x; 1.1234x over previous
//
#include <hip/hip_runtime.h>

typedef float    f4 __attribute__((ext_vector_type(4)));
typedef _Float16 h8 __attribute__((ext_vector_type(8)));
typedef _Float16 h4 __attribute__((ext_vector_type(4)));

#define DEV static __device__ __forceinline__

DEV f4 mfma16(h8 a, h8 b, f4 c) {
  return __builtin_amdgcn_mfma_f32_16x16x32_f16(a, b, c, 0, 0, 0);
}

DEV void gload16(const void* g, void* lds) {
  __builtin_amdgcn_global_load_lds((__attribute__((address_space(1))) void*)g,
                                   (__attribute__((address_space(3))) void*)lds,
                                   16, 0, 0);
}

// ---------------- fp32 -> fp16 conversion (x + packed weights) ----------------
__global__ __launch_bounds__(256) void cvt_all(
    const float* __restrict__ x,  const float* __restrict__ wq,
    const float* __restrict__ wk, const float* __restrict__ wv,
    const float* __restrict__ wo,
    _Float16* __restrict__ xb, _Float16* __restrict__ wqkv, _Float16* __restrict__ wob)
{
  int b = blockIdx.x;
  const float* src; _Float16* dst; int i4;
  if      (b < 8192)  { src = x;  dst = xb;                 i4 = b * 256; }
  else if (b < 9216)  { src = wq; dst = wqkv;               i4 = (b - 8192)  * 256; }
  else if (b < 10240) { src = wk; dst = wqkv + (1u << 20);  i4 = (b - 9216)  * 256; }
  else if (b < 11264) { src = wv; dst = wqkv + (2u << 20);  i4 = (b - 10240) * 256; }
  else                { src = wo; dst = wob;                i4 = (b - 11264) * 256; }
  i4 += threadIdx.x;
  f4 v = ((const f4*)src)[i4];
  h4 o;
  o[0] = (_Float16)v[0]; o[1] = (_Float16)v[1];
  o[2] = (_Float16)v[2]; o[3] = (_Float16)v[3];
  ((h4*)dst)[i4] = o;
}

// ---------------- GEMM: C[M,N] = A[M,K] * Bt[N,K]^T  (m97 structure) ----------
// MODE 0: write fp32 C row-major.
// MODE 1: scatter fp16 into Q [B,H,S,HD] (scaled), K [B,H,S,HD], V^T [B,H,HD,S].
template<int MODE>
__global__ __launch_bounds__(256) void gemm_bt(
    const _Float16* __restrict__ A, const _Float16* __restrict__ Bt,
    float* __restrict__ C,
    _Float16* __restrict__ Qo, _Float16* __restrict__ Ko, _Float16* __restrict__ Vo,
    int N, int Ntiles)
{
  __shared__ _Float16 Al[128 * 32];
  __shared__ _Float16 Bl[128 * 32];
  const int K = 1024;
  int bid = blockIdx.x;
  int tm = bid / Ntiles, tn = bid - tm * Ntiles;
  int m0 = tm * 128, n0 = tn * 128;
  int t = threadIdx.x, w = t >> 6, l = t & 63, lo = l & 15, hi = l >> 4;
  int wr = w >> 1, wc = w & 1;

  const _Float16* Ag = A  + (size_t)(m0 + (t >> 2)) * K + (t & 3) * 8;
  const _Float16* Bg = Bt + (size_t)(n0 + (t >> 2)) * K + (t & 3) * 8;
  _Float16* Alw = Al + w * 512;
  _Float16* Blw = Bl + w * 512;

  f4 acc[4][4] = {};

  for (int k0 = 0; k0 < K; k0 += 32) {
    if (k0) __syncthreads();
    gload16(Ag + k0,          Alw);
    gload16(Ag + 64 * K + k0, Alw + 2048);
    gload16(Bg + k0,          Blw);
    gload16(Bg + 64 * K + k0, Blw + 2048);
    __syncthreads();
    h8 a[4], b[4];
    #pragma unroll
    for (int i = 0; i < 4; ++i)
      a[i] = *(const h8*)(Al + (wr * 64 + i * 16 + lo) * 32 + hi * 8);
    #pragma unroll
    for (int i = 0; i < 4; ++i)
      b[i] = *(const h8*)(Bl + (wc * 64 + i * 16 + lo) * 32 + hi * 8);
    #pragma unroll
    for (int mi = 0; mi < 4; ++mi)
      #pragma unroll
      for (int ni = 0; ni < 4; ++ni)
        acc[mi][ni] = mfma16(a[mi], b[ni], acc[mi][ni]);
  }

  #pragma unroll
  for (int mi = 0; mi < 4; ++mi) {
    #pragma unroll
    for (int ni = 0; ni < 4; ++ni) {
      #pragma unroll
      for (int j = 0; j < 4; ++j) {
        int row = m0 + wr * 64 + mi * 16 + hi * 4 + j;
        int col = n0 + wc * 64 + ni * 16 + lo;
        float v = acc[mi][ni][j];
        if (MODE == 0) {
          C[(size_t)row * N + col] = v;
        } else {
          int which = col >> 10;
          int cw = col & 1023;
          int hh = cw >> 6, hd = cw & 63;
          int bb = row >> 11, ss = row & 2047;
          if (which == 0) {
            Qo[(size_t)(bb * 16 + hh) * 131072 + (size_t)ss * 64 + hd] =
                (_Float16)(v * 0.1803368801111137f);       // 1/8 * log2(e)
          } else if (which == 1) {
            Ko[(size_t)(bb * 16 + hh) * 131072 + (size_t)ss * 64 + hd] = (_Float16)v;
          } else {                                         // V stored transposed
            Vo[(size_t)(bb * 16 + hh) * 131072 + (size_t)hd * 2048 + ss] = (_Float16)v;
          }
        }
      }
    }
  }
}

// ---------------- causal flash attention, HD=64, S=2048 ----------------------
// grid: bh(64) x pair(8). Block does q-tiles (p, 15-p) of 128 rows -> 34 kv-iters.
// 4 waves x 32 q-rows; KVBLK=64; K and V^T staged via gload_lds (XOR-swizzled
// source), double-buffered, 1 barrier/iter; row-sum via MFMA with ones-B.
__global__ __launch_bounds__(256) void attn_kernel(
    const _Float16* __restrict__ Q, const _Float16* __restrict__ Kb,
    const _Float16* __restrict__ Vb, _Float16* __restrict__ O)
{
  __shared__ _Float16 Kl[2 * 4096];   // [buf][row 64][chunk swizzled 8][8]
  __shared__ _Float16 Vl[2 * 4096];   // same layout, rows = hd
  __shared__ _Float16 Pl[4 * 2048];   // per-wave [32 q][chunk^row 8][8]

  int bid = blockIdx.x;
  int bh = bid >> 3, pr = bid & 7;
  int t = threadIdx.x, w = t >> 6, l = t & 63, lo = l & 15, hi = l >> 4;
  int l7 = l & 7;
  const size_t hoff = (size_t)bh * 131072;
  const _Float16* Kg = Kb + hoff;
  const _Float16* Vg = Vb + hoff;     // V^T: [64 hd][2048 s]
  _Float16* Pw = Pl + w * 2048;
  int rs = t >> 3, cs = t & 7;        // staging: row(+32), 16B chunk
  int bb = bh >> 4, hh = bh & 15;

  h8 ones;
  #pragma unroll
  for (int e = 0; e < 8; ++e) ones[e] = (_Float16)1.0f;

#define STAGE(buf, kt) do {                                                    \
    const _Float16* Kt_ = Kg + (size_t)(kt) * 4096;                            \
    const _Float16* Vt_ = Vg + (size_t)(kt) * 64;                              \
    _Float16* kd = Kl + (buf) * 4096 + w * 512;                                \
    _Float16* vd = Vl + (buf) * 4096 + w * 512;                                \
    gload16(Kt_ + (size_t)rs * 64          + ((cs ^ (rs & 7)) * 8), kd);       \
    gload16(Kt_ + (size_t)(rs + 32) * 64   + ((cs ^ (rs & 7)) * 8), kd + 2048);\
    gload16(Vt_ + (size_t)rs * 2048        + ((cs ^ (rs & 7)) * 8), vd);       \
    gload16(Vt_ + (size_t)(rs + 32) * 2048 + ((cs ^ (rs & 7)) * 8), vd + 2048);\
  } while (0)

  for (int pass = 0; pass < 2; ++pass) {
    int qi = pass ? 15 - pr : pr;
    int nkt = 2 * qi + 2;

    const _Float16* Qp = Q + hoff + (size_t)(qi * 128 + w * 32 + lo) * 64 + hi * 8;
    h8 qf[2][2];
    qf[0][0] = *(const h8*)(Qp);
    qf[0][1] = *(const h8*)(Qp + 32);
    qf[1][0] = *(const h8*)(Qp + 1024);
    qf[1][1] = *(const h8*)(Qp + 1024 + 32);

    f4 acc[2][4] = {};
    float m_run[2][4], l_run[2][4];
    #pragma unroll
    for (int m = 0; m < 2; ++m)
      #pragma unroll
      for (int j = 0; j < 4; ++j) { m_run[m][j] = -1e30f; l_run[m][j] = 0.f; }

    STAGE(0, 0);
    asm volatile("s_waitcnt vmcnt(0)" ::: "memory");
    __syncthreads();

    for (int kt = 0; kt < nkt; ++kt) {
      int cur = kt & 1;
      if (kt + 1 < nkt) STAGE(cur ^ 1, kt + 1);
      const _Float16* Kc = Kl + cur * 4096;
      const _Float16* Vc = Vl + cur * 4096;

      // S = Q K^T (exp2 domain; scale folded into Q)
      f4 sc[2][4] = {};
      #pragma unroll
      for (int nf = 0; nf < 4; ++nf) {
        int row = nf * 16 + lo;
        h8 kf0 = *(const h8*)(Kc + row * 64 + ((hi       ^ (row & 7)) * 8));
        h8 kf1 = *(const h8*)(Kc + row * 64 + (((4 + hi) ^ (row & 7)) * 8));
        #pragma unroll
        for (int m = 0; m < 2; ++m) {
          sc[m][nf] = mfma16(qf[m][0], kf0, sc[m][nf]);
          sc[m][nf] = mfma16(qf[m][1], kf1, sc[m][nf]);
        }
      }

      if (kt >= 2 * qi) {             // only last two kv-tiles touch the diagonal
        #pragma unroll
        for (int m = 0; m < 2; ++m)
          #pragma unroll
          for (int nf = 0; nf < 4; ++nf) {
            int kg = kt * 64 + nf * 16 + lo;
            #pragma unroll
            for (int j = 0; j < 4; ++j) {
              int qg = qi * 128 + w * 32 + m * 16 + hi * 4 + j;
              if (kg > qg) sc[m][nf][j] = -1e30f;
            }
          }
      }

      // online max (wave-parallel width-16 reduce)
      float corr[2][4];
      #pragma unroll
      for (int m = 0; m < 2; ++m)
        #pragma unroll
        for (int j = 0; j < 4; ++j) {
          float mx = fmaxf(fmaxf(sc[m][0][j], sc[m][1][j]),
                           fmaxf(sc[m][2][j], sc[m][3][j]));
          #pragma unroll
          for (int d = 1; d < 16; d <<= 1)
            mx = fmaxf(mx, __shfl_xor(mx, d, 16));
          float mn = fmaxf(m_run[m][j], mx);
          corr[m][j] = exp2f(m_run[m][j] - mn);
          m_run[m][j] = mn;
        }

      // P = exp2(S - m) -> swizzled per-wave LDS
      #pragma unroll
      for (int m = 0; m < 2; ++m)
        #pragma unroll
        for (int nf = 0; nf < 4; ++nf)
          #pragma unroll
          for (int j = 0; j < 4; ++j) {
            float p = exp2f(sc[m][nf][j] - m_run[m][j]);
            int rq = m * 16 + hi * 4 + j;
            Pw[rq * 64 + ((((nf << 1) | (lo >> 3)) ^ (rq & 7)) * 8) + l7] =
                (_Float16)p;
          }

      #pragma unroll
      for (int m = 0; m < 2; ++m)
        #pragma unroll
        for (int nf = 0; nf < 4; ++nf)
          #pragma unroll
          for (int j = 0; j < 4; ++j)
            acc[m][nf][j] *= corr[m][j];

      __builtin_amdgcn_sched_barrier(0);
      asm volatile("s_waitcnt lgkmcnt(0)" ::: "memory");
      __builtin_amdgcn_sched_barrier(0);

      // O += P V ; row-sums via MFMA with ones-B
      f4 lacc[2] = {};
      #pragma unroll
      for (int ks = 0; ks < 2; ++ks) {
        h8 pf[2];
        #pragma unroll
        for (int m = 0; m < 2; ++m) {
          pf[m] = *(const h8*)(Pw + (m * 16 + lo) * 64 +
                               ((((ks << 2) | hi) ^ l7) * 8));
          lacc[m] = mfma16(pf[m], ones, lacc[m]);
        }
        #pragma unroll
        for (int nf = 0; nf < 4; ++nf) {
          int row = nf * 16 + lo;
          h8 vf = *(const h8*)(Vc + row * 64 + ((((ks << 2) | hi) ^ (row & 7)) * 8));
          #pragma unroll
          for (int m = 0; m < 2; ++m)
            acc[m][nf] = mfma16(pf[m], vf, acc[m][nf]);
        }
      }
      #pragma unroll
      for (int m = 0; m < 2; ++m)
        #pragma unroll
        for (int j = 0; j < 4; ++j)
          l_run[m][j] = l_run[m][j] * corr[m][j] + lacc[m][j];

      asm volatile("s_waitcnt vmcnt(0)" ::: "memory");
      __syncthreads();
    }

    #pragma unroll
    for (int m = 0; m < 2; ++m)
      #pragma unroll
      for (int j = 0; j < 4; ++j) {
        float inv = 1.0f / l_run[m][j];
        int q = qi * 128 + w * 32 + m * 16 + hi * 4 + j;
        _Float16* Op = O + ((size_t)(bb * 2048 + q)) * 1024 + hh * 64 + lo;
        #pragma unroll
        for (int nf = 0; nf < 4; ++nf)
          Op[nf * 16] = (_Float16)(acc[m][nf][j] * inv);
      }
  }
#undef STAGE
}

extern "C" void kernel_launch(void* const* d_in, const int* in_sizes, int n_in,
                              void* d_out, int out_size, void* d_ws, size_t ws_size,
                              hipStream_t stream)
{
  const float* x  = (const float*)d_in[0];
  const float* wq = (const float*)d_in[1];
  const float* wk = (const float*)d_in[2];
  const float* wv = (const float*)d_in[3];
  const float* wo = (const float*)d_in[4];
  // d_in[5] = causal mask: implemented analytically.

  char* ws = (char*)d_ws;
  _Float16* xb   = (_Float16*)(ws);                  // 16 MB, reused as Ob later
  _Float16* wqkv = (_Float16*)(ws + (16u << 20));    //  6 MB
  _Float16* wob  = (_Float16*)(ws + (22u << 20));    //  2 MB
  _Float16* Qb   = (_Float16*)(ws + (24u << 20));    // 16 MB
  _Float16* Kb   = (_Float16*)(ws + (40u << 20));    // 16 MB
  _Float16* Vb   = (_Float16*)(ws + (56u << 20));    // 16 MB (transposed)
  _Float16* Ob   = xb;                               // xb dead after QKV GEMM

  cvt_all<<<12288, 256, 0, stream>>>(x, wq, wk, wv, wo, xb, wqkv, wob);
  gemm_bt<1><<<64 * 24, 256, 0, stream>>>(xb, wqkv, nullptr, Qb, Kb, Vb, 3072, 24);
  attn_kernel<<<512, 256, 0, stream>>>(Qb, Kb, Vb, Ob);
  gemm_bt<0><<<64 * 8, 256, 0, stream>>>(Ob, wob, (float*)d_out,
                                         nullptr, nullptr, nullptr, 1024, 8);
}

// Round 3
// 225.953 us; speedup vs baseline: 1.5349x; 1.3663x over previous
//
#include <hip/hip_runtime.h>

typedef float    f4 __attribute__((ext_vector_type(4)));
typedef _Float16 h8 __attribute__((ext_vector_type(8)));
typedef _Float16 h4 __attribute__((ext_vector_type(4)));
typedef _Float16 h2 __attribute__((ext_vector_type(2)));

#define DEV static __device__ __forceinline__

DEV f4 mfma16(h8 a, h8 b, f4 c) {
  return __builtin_amdgcn_mfma_f32_16x16x32_f16(a, b, c, 0, 0, 0);
}

DEV void gload16(const void* g, void* lds) {
  __builtin_amdgcn_global_load_lds((__attribute__((address_space(1))) void*)g,
                                   (__attribute__((address_space(3))) void*)lds,
                                   16, 0, 0);
}

DEV h2 cvtpk(float a, float b) {
  return __builtin_bit_cast(h2, __builtin_amdgcn_cvt_pkrtz(a, b));
}

// ---------------- fp32 -> fp16 conversion (x + packed weights) ----------------
__global__ __launch_bounds__(256) void cvt_all(
    const float* __restrict__ x,  const float* __restrict__ wq,
    const float* __restrict__ wk, const float* __restrict__ wv,
    const float* __restrict__ wo,
    _Float16* __restrict__ xb, _Float16* __restrict__ wqkv, _Float16* __restrict__ wob)
{
  int b = blockIdx.x;
  const float* src; _Float16* dst; int i4;
  if      (b < 8192)  { src = x;  dst = xb;                 i4 = b * 256; }
  else if (b < 9216)  { src = wq; dst = wqkv;               i4 = (b - 8192)  * 256; }
  else if (b < 10240) { src = wk; dst = wqkv + (1u << 20);  i4 = (b - 9216)  * 256; }
  else if (b < 11264) { src = wv; dst = wqkv + (2u << 20);  i4 = (b - 10240) * 256; }
  else                { src = wo; dst = wob;                i4 = (b - 11264) * 256; }
  i4 += threadIdx.x;
  f4 v = ((const f4*)src)[i4];
  h4 o;
  o[0] = (_Float16)v[0]; o[1] = (_Float16)v[1];
  o[2] = (_Float16)v[2]; o[3] = (_Float16)v[3];
  ((h4*)dst)[i4] = o;
}

// ---------------- GEMM: C[M,N] = A[M,K] * Bt[N,K]^T  (m97 structure) ----------
// MODE 0: write fp32 C row-major.
// MODE 1: scatter fp16 into Q [B,H,S,HD] (scaled), K [B,H,S,HD], V^T [B,H,HD,S].
template<int MODE>
__global__ __launch_bounds__(256) void gemm_bt(
    const _Float16* __restrict__ A, const _Float16* __restrict__ Bt,
    float* __restrict__ C,
    _Float16* __restrict__ Qo, _Float16* __restrict__ Ko, _Float16* __restrict__ Vo,
    int N, int Ntiles)
{
  __shared__ _Float16 Al[128 * 32];
  __shared__ _Float16 Bl[128 * 32];
  const int K = 1024;
  int bid = blockIdx.x;
  int tm = bid / Ntiles, tn = bid - tm * Ntiles;
  int m0 = tm * 128, n0 = tn * 128;
  int t = threadIdx.x, w = t >> 6, l = t & 63, lo = l & 15, hi = l >> 4;
  int wr = w >> 1, wc = w & 1;

  const _Float16* Ag = A  + (size_t)(m0 + (t >> 2)) * K + (t & 3) * 8;
  const _Float16* Bg = Bt + (size_t)(n0 + (t >> 2)) * K + (t & 3) * 8;
  _Float16* Alw = Al + w * 512;
  _Float16* Blw = Bl + w * 512;

  f4 acc[4][4] = {};

  for (int k0 = 0; k0 < K; k0 += 32) {
    if (k0) __syncthreads();
    gload16(Ag + k0,          Alw);
    gload16(Ag + 64 * K + k0, Alw + 2048);
    gload16(Bg + k0,          Blw);
    gload16(Bg + 64 * K + k0, Blw + 2048);
    __syncthreads();
    h8 a[4], b[4];
    #pragma unroll
    for (int i = 0; i < 4; ++i)
      a[i] = *(const h8*)(Al + (wr * 64 + i * 16 + lo) * 32 + hi * 8);
    #pragma unroll
    for (int i = 0; i < 4; ++i)
      b[i] = *(const h8*)(Bl + (wc * 64 + i * 16 + lo) * 32 + hi * 8);
    #pragma unroll
    for (int mi = 0; mi < 4; ++mi)
      #pragma unroll
      for (int ni = 0; ni < 4; ++ni)
        acc[mi][ni] = mfma16(a[mi], b[ni], acc[mi][ni]);
  }

  #pragma unroll
  for (int mi = 0; mi < 4; ++mi) {
    #pragma unroll
    for (int ni = 0; ni < 4; ++ni) {
      #pragma unroll
      for (int j = 0; j < 4; ++j) {
        int row = m0 + wr * 64 + mi * 16 + hi * 4 + j;
        int col = n0 + wc * 64 + ni * 16 + lo;
        float v = acc[mi][ni][j];
        if (MODE == 0) {
          C[(size_t)row * N + col] = v;
        } else {
          int which = col >> 10;
          int cw = col & 1023;
          int hh = cw >> 6, hd = cw & 63;
          int bb = row >> 11, ss = row & 2047;
          if (which == 0) {
            Qo[(size_t)(bb * 16 + hh) * 131072 + (size_t)ss * 64 + hd] =
                (_Float16)(v * 0.1803368801111137f);       // 1/8 * log2(e)
          } else if (which == 1) {
            Ko[(size_t)(bb * 16 + hh) * 131072 + (size_t)ss * 64 + hd] = (_Float16)v;
          } else {                                         // V stored transposed
            Vo[(size_t)(bb * 16 + hh) * 131072 + (size_t)hd * 2048 + ss] = (_Float16)v;
          }
        }
      }
    }
  }
}

// ---------------- causal flash attention, HD=64, S=2048 ----------------------
// grid: bh(64) x pair(16). Block = 2 waves x 32 q-rows = 64 q-rows; does
// q-tiles (p, 31-p) -> 33 kv-iters uniform. Swapped QK^T (S^T = mfma(K,Q)):
// lane holds a full 16-k slice of one q-row -> in-register softmax; P spilled
// per-wave as 8x ds_write_b64 (chunk-XOR swizzle), read back as B-fragments.
__global__ __launch_bounds__(128) void attn_kernel(
    const _Float16* __restrict__ Q, const _Float16* __restrict__ Kb,
    const _Float16* __restrict__ Vb, _Float16* __restrict__ O)
{
  __shared__ _Float16 Kl[2 * 4096];   // [buf][row 64][chunk^row 8][8]
  __shared__ _Float16 Vl[2 * 4096];   // same, rows = hd (V^T)
  __shared__ _Float16 Pl[2 * 2048];   // per-wave [2 m][16 q][chunk^q 16][4]

  int bid = blockIdx.x;
  int bh = bid >> 4, pr = bid & 15;
  int t = threadIdx.x, w = t >> 6, l = t & 63, lo = l & 15, hi = l >> 4;
  const size_t hoff = (size_t)bh * 131072;
  const _Float16* Kg = Kb + hoff;
  const _Float16* Vg = Vb + hoff;     // V^T: [64 hd][2048 s]
  _Float16* Pw = Pl + w * 2048;
  int rs = t >> 3, cs = t & 7;        // staging: row 0..15 (+16k), 16B chunk
  int bb = bh >> 4, hh = bh & 15;
  int swz = (lo & 7) << 1;            // P chunk-XOR (even -> b128-safe)

  h8 ones;
  #pragma unroll
  for (int e = 0; e < 8; ++e) ones[e] = (_Float16)1.0f;

#define STAGE(buf, kt) do {                                                   \
    const _Float16* Kt_ = Kg + (size_t)(kt) * 4096;                           \
    const _Float16* Vt_ = Vg + (size_t)(kt) * 64;                             \
    _Float16* kd = Kl + (buf) * 4096 + w * 512;                               \
    _Float16* vd = Vl + (buf) * 4096 + w * 512;                               \
    int sw_ = (cs ^ (rs & 7)) * 8;                                            \
    gload16(Kt_ + (size_t)rs * 64 + sw_,          kd);                        \
    gload16(Kt_ + (size_t)(rs + 16) * 64 + sw_,   kd + 1024);                 \
    gload16(Kt_ + (size_t)(rs + 32) * 64 + sw_,   kd + 2048);                 \
    gload16(Kt_ + (size_t)(rs + 48) * 64 + sw_,   kd + 3072);                 \
    gload16(Vt_ + (size_t)rs * 2048 + sw_,        vd);                        \
    gload16(Vt_ + (size_t)(rs + 16) * 2048 + sw_, vd + 1024);                 \
    gload16(Vt_ + (size_t)(rs + 32) * 2048 + sw_, vd + 2048);                 \
    gload16(Vt_ + (size_t)(rs + 48) * 2048 + sw_, vd + 3072);                 \
  } while (0)

  for (int pass = 0; pass < 2; ++pass) {
    int qi = pass ? 31 - pr : pr;
    int nkt = qi + 1;
    int qb = qi * 64 + w * 32;

    const _Float16* Qp = Q + hoff + (size_t)(qb + lo) * 64 + hi * 8;
    h8 qf[2][2];
    qf[0][0] = *(const h8*)(Qp);
    qf[0][1] = *(const h8*)(Qp + 32);
    qf[1][0] = *(const h8*)(Qp + 1024);
    qf[1][1] = *(const h8*)(Qp + 1056);

    f4 acc[2][4] = {};
    float m_run[2] = {-1e30f, -1e30f};
    float l_run[2] = {0.f, 0.f};

    STAGE(0, 0);
    asm volatile("s_waitcnt vmcnt(0)" ::: "memory");
    __syncthreads();

    for (int kt = 0; kt < nkt; ++kt) {
      int cur = kt & 1;
      if (kt + 1 < nkt) STAGE(cur ^ 1, kt + 1);
      const _Float16* Kc = Kl + cur * 4096;
      const _Float16* Vc = Vl + cur * 4096;

      // S^T = K Q^T : lane holds k = kf*16 + hi*4 + j for q-row (m*16 + lo)
      f4 sc[2][4] = {};
      #pragma unroll
      for (int kf = 0; kf < 4; ++kf) {
        int row = kf * 16 + lo;
        h8 k0 = *(const h8*)(Kc + row * 64 + ((hi       ^ (row & 7)) * 8));
        h8 k1 = *(const h8*)(Kc + row * 64 + (((4 + hi) ^ (row & 7)) * 8));
        #pragma unroll
        for (int m = 0; m < 2; ++m) {
          sc[m][kf] = mfma16(k0, qf[m][0], sc[m][kf]);
          sc[m][kf] = mfma16(k1, qf[m][1], sc[m][kf]);
        }
      }

      if (kt == nkt - 1) {            // only the last kv-tile hits the diagonal
        #pragma unroll
        for (int m = 0; m < 2; ++m) {
          int qg = qb + m * 16 + lo;
          #pragma unroll
          for (int kf = 0; kf < 4; ++kf) {
            int kgb = kt * 64 + kf * 16 + hi * 4;
            #pragma unroll
            for (int j = 0; j < 4; ++j)
              if (kgb + j > qg) sc[m][kf][j] = -1e30f;
          }
        }
      }

      // in-register online softmax (exp2 domain)
      float corrv[2];
      #pragma unroll
      for (int m = 0; m < 2; ++m) {
        f4 m4 = sc[m][0];
        #pragma unroll
        for (int kf = 1; kf < 4; ++kf) {
          m4[0] = fmaxf(m4[0], sc[m][kf][0]); m4[1] = fmaxf(m4[1], sc[m][kf][1]);
          m4[2] = fmaxf(m4[2], sc[m][kf][2]); m4[3] = fmaxf(m4[3], sc[m][kf][3]);
        }
        float mx = fmaxf(fmaxf(m4[0], m4[1]), fmaxf(m4[2], m4[3]));
        mx = fmaxf(mx, __shfl_xor(mx, 16));
        mx = fmaxf(mx, __shfl_xor(mx, 32));
        float mn = fmaxf(m_run[m], mx);
        corrv[m] = exp2f(m_run[m] - mn);
        m_run[m] = mn;

        #pragma unroll
        for (int kf = 0; kf < 4; ++kf) {
          float p0 = exp2f(sc[m][kf][0] - mn);
          float p1 = exp2f(sc[m][kf][1] - mn);
          float p2 = exp2f(sc[m][kf][2] - mn);
          float p3 = exp2f(sc[m][kf][3] - mn);
          h4 pk;
          pk.xy = cvtpk(p0, p1);
          pk.zw = cvtpk(p2, p3);
          int c = ((kf << 2) | hi) ^ swz;
          *(h4*)(Pw + m * 1024 + lo * 64 + c * 4) = pk;
        }
        #pragma unroll
        for (int df = 0; df < 4; ++df) acc[m][df] *= corrv[m];
      }

      __builtin_amdgcn_sched_barrier(0);
      asm volatile("s_waitcnt lgkmcnt(0)" ::: "memory");
      __builtin_amdgcn_sched_barrier(0);

      // O^T += V^T P^T ; row-sums via ones-A MFMA on the same P fragments
      f4 ls[2] = {};
      #pragma unroll
      for (int ks = 0; ks < 2; ++ks) {
        h8 pf[2];
        #pragma unroll
        for (int m = 0; m < 2; ++m) {
          int c0 = ((ks << 3) | (hi << 1)) ^ swz;
          pf[m] = *(const h8*)(Pw + m * 1024 + lo * 64 + c0 * 4);
          ls[m] = mfma16(ones, pf[m], ls[m]);
        }
        #pragma unroll
        for (int df = 0; df < 4; ++df) {
          int row = df * 16 + lo;
          h8 vf = *(const h8*)(Vc + row * 64 + ((((ks << 2) | hi) ^ (row & 7)) * 8));
          #pragma unroll
          for (int m = 0; m < 2; ++m)
            acc[m][df] = mfma16(vf, pf[m], acc[m][df]);
        }
      }
      #pragma unroll
      for (int m = 0; m < 2; ++m)
        l_run[m] = l_run[m] * corrv[m] + ls[m][0];

      asm volatile("s_waitcnt vmcnt(0)" ::: "memory");
      __syncthreads();
    }

    // epilogue: lane (hi,lo) holds O[q = qb+m*16+lo][d = df*16+hi*4+j]
    #pragma unroll
    for (int m = 0; m < 2; ++m) {
      float inv = 1.0f / l_run[m];
      int q = qb + m * 16 + lo;
      _Float16* Op = O + ((size_t)(bb * 2048 + q)) * 1024 + hh * 64 + (hi << 2);
      #pragma unroll
      for (int df = 0; df < 4; ++df) {
        h4 o4;
        o4[0] = (_Float16)(acc[m][df][0] * inv);
        o4[1] = (_Float16)(acc[m][df][1] * inv);
        o4[2] = (_Float16)(acc[m][df][2] * inv);
        o4[3] = (_Float16)(acc[m][df][3] * inv);
        *(h4*)(Op + df * 16) = o4;
      }
    }
  }
#undef STAGE
}

extern "C" void kernel_launch(void* const* d_in, const int* in_sizes, int n_in,
                              void* d_out, int out_size, void* d_ws, size_t ws_size,
                              hipStream_t stream)
{
  const float* x  = (const float*)d_in[0];
  const float* wq = (const float*)d_in[1];
  const float* wk = (const float*)d_in[2];
  const float* wv = (const float*)d_in[3];
  const float* wo = (const float*)d_in[4];
  // d_in[5] = causal mask: implemented analytically.

  char* ws = (char*)d_ws;
  _Float16* xb   = (_Float16*)(ws);                  // 16 MB, reused as Ob later
  _Float16* wqkv = (_Float16*)(ws + (16u << 20));    //  6 MB
  _Float16* wob  = (_Float16*)(ws + (22u << 20));    //  2 MB
  _Float16* Qb   = (_Float16*)(ws + (24u << 20));    // 16 MB
  _Float16* Kb   = (_Float16*)(ws + (40u << 20));    // 16 MB
  _Float16* Vb   = (_Float16*)(ws + (56u << 20));    // 16 MB (transposed)
  _Float16* Ob   = xb;                               // xb dead after QKV GEMM

  cvt_all<<<12288, 256, 0, stream>>>(x, wq, wk, wv, wo, xb, wqkv, wob);
  gemm_bt<1><<<64 * 24, 256, 0, stream>>>(xb, wqkv, nullptr, Qb, Kb, Vb, 3072, 24);
  attn_kernel<<<1024, 128, 0, stream>>>(Qb, Kb, Vb, Ob);
  gemm_bt<0><<<64 * 8, 256, 0, stream>>>(Ob, wob, (float*)d_out,
                                         nullptr, nullptr, nullptr, 1024, 8);
}

// Round 4
// 200.012 us; speedup vs baseline: 1.7340x; 1.1297x over previous
//
#include <hip/hip_runtime.h>

typedef float    f4 __attribute__((ext_vector_type(4)));
typedef _Float16 h8 __attribute__((ext_vector_type(8)));
typedef _Float16 h4 __attribute__((ext_vector_type(4)));
typedef _Float16 h2 __attribute__((ext_vector_type(2)));

#define DEV static __device__ __forceinline__

DEV f4 mfma16(h8 a, h8 b, f4 c) {
  return __builtin_amdgcn_mfma_f32_16x16x32_f16(a, b, c, 0, 0, 0);
}

DEV void gload16(const void* g, void* lds) {
  __builtin_amdgcn_global_load_lds((__attribute__((address_space(1))) void*)g,
                                   (__attribute__((address_space(3))) void*)lds,
                                   16, 0, 0);
}

DEV h2 cvtpk(float a, float b) {
  return __builtin_bit_cast(h2, __builtin_amdgcn_cvt_pkrtz(a, b));
}

// ---------------- fp32 -> fp16 conversion (x + packed weights) ----------------
__global__ __launch_bounds__(256) void cvt_all(
    const float* __restrict__ x,  const float* __restrict__ wq,
    const float* __restrict__ wk, const float* __restrict__ wv,
    const float* __restrict__ wo,
    _Float16* __restrict__ xb, _Float16* __restrict__ wqkv, _Float16* __restrict__ wob)
{
  int b = blockIdx.x;
  const float* src; _Float16* dst; int i4;
  if      (b < 8192)  { src = x;  dst = xb;                 i4 = b * 256; }
  else if (b < 9216)  { src = wq; dst = wqkv;               i4 = (b - 8192)  * 256; }
  else if (b < 10240) { src = wk; dst = wqkv + (1u << 20);  i4 = (b - 9216)  * 256; }
  else if (b < 11264) { src = wv; dst = wqkv + (2u << 20);  i4 = (b - 10240) * 256; }
  else                { src = wo; dst = wob;                i4 = (b - 11264) * 256; }
  i4 += threadIdx.x;
  f4 v = ((const f4*)src)[i4];
  h4 o;
  o[0] = (_Float16)v[0]; o[1] = (_Float16)v[1];
  o[2] = (_Float16)v[2]; o[3] = (_Float16)v[3];
  ((h4*)dst)[i4] = o;
}

// ---------------- GEMM: C[M,N] = A[M,K] * Bt[N,K]^T  (m97 structure) ----------
// MODE 0: write fp32 C row-major.
// MODE 1: scatter fp16 into Q [B,H,S,HD] (scaled), K [B,H,S,HD], V^T [B,H,HD,S].
template<int MODE>
__global__ __launch_bounds__(256) void gemm_bt(
    const _Float16* __restrict__ A, const _Float16* __restrict__ Bt,
    float* __restrict__ C,
    _Float16* __restrict__ Qo, _Float16* __restrict__ Ko, _Float16* __restrict__ Vo,
    int N, int Ntiles)
{
  __shared__ _Float16 Al[128 * 32];
  __shared__ _Float16 Bl[128 * 32];
  const int K = 1024;
  int bid = blockIdx.x;
  int tm = bid / Ntiles, tn = bid - tm * Ntiles;
  int m0 = tm * 128, n0 = tn * 128;
  int t = threadIdx.x, w = t >> 6, l = t & 63, lo = l & 15, hi = l >> 4;
  int wr = w >> 1, wc = w & 1;

  const _Float16* Ag = A  + (size_t)(m0 + (t >> 2)) * K + (t & 3) * 8;
  const _Float16* Bg = Bt + (size_t)(n0 + (t >> 2)) * K + (t & 3) * 8;
  _Float16* Alw = Al + w * 512;
  _Float16* Blw = Bl + w * 512;

  f4 acc[4][4] = {};

  for (int k0 = 0; k0 < K; k0 += 32) {
    if (k0) __syncthreads();
    gload16(Ag + k0,          Alw);
    gload16(Ag + 64 * K + k0, Alw + 2048);
    gload16(Bg + k0,          Blw);
    gload16(Bg + 64 * K + k0, Blw + 2048);
    __syncthreads();
    h8 a[4], b[4];
    #pragma unroll
    for (int i = 0; i < 4; ++i)
      a[i] = *(const h8*)(Al + (wr * 64 + i * 16 + lo) * 32 + hi * 8);
    #pragma unroll
    for (int i = 0; i < 4; ++i)
      b[i] = *(const h8*)(Bl + (wc * 64 + i * 16 + lo) * 32 + hi * 8);
    #pragma unroll
    for (int mi = 0; mi < 4; ++mi)
      #pragma unroll
      for (int ni = 0; ni < 4; ++ni)
        acc[mi][ni] = mfma16(a[mi], b[ni], acc[mi][ni]);
  }

  #pragma unroll
  for (int mi = 0; mi < 4; ++mi) {
    #pragma unroll
    for (int ni = 0; ni < 4; ++ni) {
      #pragma unroll
      for (int j = 0; j < 4; ++j) {
        int row = m0 + wr * 64 + mi * 16 + hi * 4 + j;
        int col = n0 + wc * 64 + ni * 16 + lo;
        float v = acc[mi][ni][j];
        if (MODE == 0) {
          C[(size_t)row * N + col] = v;
        } else {
          int which = col >> 10;
          int cw = col & 1023;
          int hh = cw >> 6, hd = cw & 63;
          int bb = row >> 11, ss = row & 2047;
          if (which == 0) {
            Qo[(size_t)(bb * 16 + hh) * 131072 + (size_t)ss * 64 + hd] =
                (_Float16)(v * 0.1803368801111137f);       // 1/8 * log2(e)
          } else if (which == 1) {
            Ko[(size_t)(bb * 16 + hh) * 131072 + (size_t)ss * 64 + hd] = (_Float16)v;
          } else {                                         // V stored transposed
            Vo[(size_t)(bb * 16 + hh) * 131072 + (size_t)hd * 2048 + ss] = (_Float16)v;
          }
        }
      }
    }
  }
}

// ---------------- causal flash attention, HD=64, S=2048 ----------------------
// grid 1024: bh = bid&63 (XCD = bh%8 -> per-head L2 locality), qi = 15-(bid>>6)
// (longest blocks first). Block = 4 waves x 32 q-rows = QBLK 128; KVBLK=64,
// double-buffered; nkt = 2qi+2 (even) -> kv-loop unrolled x2 with static bufs.
// Swapped QK^T -> in-register softmax with defer-max (THR=8, exp2 domain).
__global__ __launch_bounds__(256, 3) void attn_kernel(
    const _Float16* __restrict__ Q, const _Float16* __restrict__ Kb,
    const _Float16* __restrict__ Vb, _Float16* __restrict__ O)
{
  __shared__ _Float16 Kl[2 * 4096];   // [buf][row 64][chunk^row 8][8]
  __shared__ _Float16 Vl[2 * 4096];   // same, rows = hd (V^T)
  __shared__ _Float16 Pl[4 * 2048];   // per-wave [2 m][16 q][chunk^q 16][4]

  int bid = blockIdx.x;
  int bh = bid & 63, qi = 15 - (bid >> 6);
  int t = threadIdx.x, w = t >> 6, l = t & 63, lo = l & 15, hi = l >> 4;
  const size_t hoff = (size_t)bh * 131072;
  const _Float16* Kg = Kb + hoff;
  const _Float16* Vg = Vb + hoff;     // V^T: [64 hd][2048 s]
  _Float16* Pw = Pl + w * 2048;
  int bb = bh >> 4, hh = bh & 15;
  int swz = (lo & 7) << 1;            // P chunk-XOR (even -> b128-safe)

  // ---- hoisted staging source/dest offsets (elements) ----
  int rs = t >> 3, cs = t & 7;        // rows 0..31 (+32), 16B chunk
  int sw_ = (cs ^ (rs & 7)) * 8;
  int srcK0 = rs * 64 + sw_,   srcK1 = srcK0 + 2048;
  int srcV0 = rs * 2048 + sw_, srcV1 = srcV0 + 65536;
  _Float16* kd0 = Kl + w * 512;
  _Float16* vd0 = Vl + w * 512;

  // ---- hoisted LDS fragment offsets (elements) ----
  int koff[4][2], voff[2][4], pwoff[2][4], proff[2][2];
  #pragma unroll
  for (int kf = 0; kf < 4; ++kf) {
    int row = kf * 16 + lo;
    koff[kf][0] = row * 64 + ((hi       ^ (row & 7)) * 8);
    koff[kf][1] = row * 64 + (((4 + hi) ^ (row & 7)) * 8);
  }
  #pragma unroll
  for (int ks = 0; ks < 2; ++ks)
    #pragma unroll
    for (int df = 0; df < 4; ++df) {
      int row = df * 16 + lo;
      voff[ks][df] = row * 64 + ((((ks << 2) | hi) ^ (row & 7)) * 8);
    }
  #pragma unroll
  for (int m = 0; m < 2; ++m) {
    #pragma unroll
    for (int kf = 0; kf < 4; ++kf)
      pwoff[m][kf] = m * 1024 + lo * 64 + ((((kf << 2) | hi) ^ swz) * 4);
    #pragma unroll
    for (int ks = 0; ks < 2; ++ks)
      proff[m][ks] = m * 1024 + lo * 64 + ((((ks << 3) | (hi << 1)) ^ swz) * 4);
  }

  h8 ones;
  #pragma unroll
  for (int e = 0; e < 8; ++e) ones[e] = (_Float16)1.0f;

  int qb = qi * 128 + w * 32;
  const _Float16* Qp = Q + hoff + (size_t)(qb + lo) * 64 + hi * 8;
  h8 qf[2][2];
  qf[0][0] = *(const h8*)(Qp);
  qf[0][1] = *(const h8*)(Qp + 32);
  qf[1][0] = *(const h8*)(Qp + 1024);
  qf[1][1] = *(const h8*)(Qp + 1056);

  f4 acc[2][4] = {};
  float m_run[2] = {-1e30f, -1e30f};
  float l_run[2] = {0.f, 0.f};
  int nkt = 2 * qi + 2;

#define STAGE(buf, kt) do {                                                   \
    const _Float16* Kt_ = Kg + (size_t)(kt) * 4096;                           \
    const _Float16* Vt_ = Vg + (size_t)(kt) * 64;                             \
    gload16(Kt_ + srcK0, kd0 + (buf) * 4096);                                 \
    gload16(Kt_ + srcK1, kd0 + (buf) * 4096 + 2048);                          \
    gload16(Vt_ + srcV0, vd0 + (buf) * 4096);                                 \
    gload16(Vt_ + srcV1, vd0 + (buf) * 4096 + 2048);                          \
  } while (0)

#define ITER(kt, buf) do {                                                    \
    if ((kt) + 1 < nkt) STAGE(buf ^ 1, (kt) + 1);                             \
    const _Float16* Kc = Kl + (buf) * 4096;                                   \
    const _Float16* Vc = Vl + (buf) * 4096;                                   \
    f4 sc[2][4] = {};                                                         \
    __builtin_amdgcn_s_setprio(1);                                            \
    _Pragma("unroll")                                                         \
    for (int kf = 0; kf < 4; ++kf) {                                          \
      h8 k0 = *(const h8*)(Kc + koff[kf][0]);                                 \
      h8 k1 = *(const h8*)(Kc + koff[kf][1]);                                 \
      _Pragma("unroll")                                                       \
      for (int m = 0; m < 2; ++m) {                                           \
        sc[m][kf] = mfma16(k0, qf[m][0], sc[m][kf]);                          \
        sc[m][kf] = mfma16(k1, qf[m][1], sc[m][kf]);                          \
      }                                                                       \
    }                                                                         \
    __builtin_amdgcn_s_setprio(0);                                            \
    if ((kt) >= 2 * qi) {                                                     \
      _Pragma("unroll")                                                       \
      for (int m = 0; m < 2; ++m) {                                           \
        int qg = qb + m * 16 + lo;                                            \
        _Pragma("unroll")                                                     \
        for (int kf = 0; kf < 4; ++kf) {                                      \
          int kgb = (kt) * 64 + kf * 16 + hi * 4;                             \
          _Pragma("unroll")                                                   \
          for (int j = 0; j < 4; ++j)                                         \
            if (kgb + j > qg) sc[m][kf][j] = -1e30f;                          \
        }                                                                     \
      }                                                                       \
    }                                                                         \
    _Pragma("unroll")                                                         \
    for (int m = 0; m < 2; ++m) {                                             \
      f4 m4 = sc[m][0];                                                       \
      _Pragma("unroll")                                                       \
      for (int kf = 1; kf < 4; ++kf) {                                        \
        m4[0] = fmaxf(m4[0], sc[m][kf][0]); m4[1] = fmaxf(m4[1], sc[m][kf][1]);\
        m4[2] = fmaxf(m4[2], sc[m][kf][2]); m4[3] = fmaxf(m4[3], sc[m][kf][3]);\
      }                                                                       \
      float mx = fmaxf(fmaxf(m4[0], m4[1]), fmaxf(m4[2], m4[3]));             \
      if (!__all(mx <= m_run[m] + 8.f)) {     /* defer-max: rare path */      \
        mx = fmaxf(mx, __shfl_xor(mx, 16));                                   \
        mx = fmaxf(mx, __shfl_xor(mx, 32));                                   \
        float mn = fmaxf(m_run[m], mx);                                       \
        float cr = exp2f(m_run[m] - mn);                                      \
        m_run[m] = mn;                                                        \
        l_run[m] *= cr;                                                       \
        _Pragma("unroll")                                                     \
        for (int df = 0; df < 4; ++df) {                                      \
          acc[m][df][0] *= cr; acc[m][df][1] *= cr;                           \
          acc[m][df][2] *= cr; acc[m][df][3] *= cr;                           \
        }                                                                     \
      }                                                                       \
      float mn = m_run[m];                                                    \
      _Pragma("unroll")                                                       \
      for (int kf = 0; kf < 4; ++kf) {                                        \
        h4 pk;                                                                \
        pk.xy = cvtpk(exp2f(sc[m][kf][0] - mn), exp2f(sc[m][kf][1] - mn));    \
        pk.zw = cvtpk(exp2f(sc[m][kf][2] - mn), exp2f(sc[m][kf][3] - mn));    \
        *(h4*)(Pw + pwoff[m][kf]) = pk;                                       \
      }                                                                       \
    }                                                                         \
    __builtin_amdgcn_sched_barrier(0);                                        \
    asm volatile("s_waitcnt lgkmcnt(0)" ::: "memory");                        \
    __builtin_amdgcn_sched_barrier(0);                                        \
    f4 ls[2] = {};                                                            \
    __builtin_amdgcn_s_setprio(1);                                            \
    _Pragma("unroll")                                                         \
    for (int ks = 0; ks < 2; ++ks) {                                          \
      h8 pf[2];                                                               \
      _Pragma("unroll")                                                       \
      for (int m = 0; m < 2; ++m) {                                           \
        pf[m] = *(const h8*)(Pw + proff[m][ks]);                              \
        ls[m] = mfma16(ones, pf[m], ls[m]);                                   \
      }                                                                       \
      _Pragma("unroll")                                                       \
      for (int df = 0; df < 4; ++df) {                                        \
        h8 vf = *(const h8*)(Vc + voff[ks][df]);                              \
        _Pragma("unroll")                                                     \
        for (int m = 0; m < 2; ++m)                                           \
          acc[m][df] = mfma16(vf, pf[m], acc[m][df]);                         \
      }                                                                       \
    }                                                                         \
    __builtin_amdgcn_s_setprio(0);                                            \
    l_run[0] += ls[0][0];                                                     \
    l_run[1] += ls[1][0];                                                     \
    asm volatile("s_waitcnt vmcnt(0)" ::: "memory");                          \
    __syncthreads();                                                          \
  } while (0)

  STAGE(0, 0);
  asm volatile("s_waitcnt vmcnt(0)" ::: "memory");
  __syncthreads();

  for (int kt = 0; kt < nkt; kt += 2) {
    ITER(kt, 0);
    ITER(kt + 1, 1);
  }

  // epilogue: lane (hi,lo) holds O[q = qb+m*16+lo][d = df*16+hi*4+j]
  #pragma unroll
  for (int m = 0; m < 2; ++m) {
    float inv = 1.0f / l_run[m];
    int q = qb + m * 16 + lo;
    _Float16* Op = O + ((size_t)(bb * 2048 + q)) * 1024 + hh * 64 + (hi << 2);
    #pragma unroll
    for (int df = 0; df < 4; ++df) {
      h4 o4;
      o4[0] = (_Float16)(acc[m][df][0] * inv);
      o4[1] = (_Float16)(acc[m][df][1] * inv);
      o4[2] = (_Float16)(acc[m][df][2] * inv);
      o4[3] = (_Float16)(acc[m][df][3] * inv);
      *(h4*)(Op + df * 16) = o4;
    }
  }
#undef ITER
#undef STAGE
}

extern "C" void kernel_launch(void* const* d_in, const int* in_sizes, int n_in,
                              void* d_out, int out_size, void* d_ws, size_t ws_size,
                              hipStream_t stream)
{
  const float* x  = (const float*)d_in[0];
  const float* wq = (const float*)d_in[1];
  const float* wk = (const float*)d_in[2];
  const float* wv = (const float*)d_in[3];
  const float* wo = (const float*)d_in[4];
  // d_in[5] = causal mask: implemented analytically.

  char* ws = (char*)d_ws;
  _Float16* xb   = (_Float16*)(ws);                  // 16 MB, reused as Ob later
  _Float16* wqkv = (_Float16*)(ws + (16u << 20));    //  6 MB
  _Float16* wob  = (_Float16*)(ws + (22u << 20));    //  2 MB
  _Float16* Qb   = (_Float16*)(ws + (24u << 20));    // 16 MB
  _Float16* Kb   = (_Float16*)(ws + (40u << 20));    // 16 MB
  _Float16* Vb   = (_Float16*)(ws + (56u << 20));    // 16 MB (transposed)
  _Float16* Ob   = xb;                               // xb dead after QKV GEMM

  cvt_all<<<12288, 256, 0, stream>>>(x, wq, wk, wv, wo, xb, wqkv, wob);
  gemm_bt<1><<<64 * 24, 256, 0, stream>>>(xb, wqkv, nullptr, Qb, Kb, Vb, 3072, 24);
  attn_kernel<<<1024, 256, 0, stream>>>(Qb, Kb, Vb, Ob);
  gemm_bt<0><<<64 * 8, 256, 0, stream>>>(Ob, wob, (float*)d_out,
                                         nullptr, nullptr, nullptr, 1024, 8);
}

// Round 5
// 192.429 us; speedup vs baseline: 1.8023x; 1.0394x over previous
//
#include <hip/hip_runtime.h>

typedef float    f4 __attribute__((ext_vector_type(4)));
typedef _Float16 h8 __attribute__((ext_vector_type(8)));
typedef _Float16 h4 __attribute__((ext_vector_type(4)));
typedef _Float16 h2 __attribute__((ext_vector_type(2)));

#define DEV static __device__ __forceinline__

DEV f4 mfma16(h8 a, h8 b, f4 c) {
  return __builtin_amdgcn_mfma_f32_16x16x32_f16(a, b, c, 0, 0, 0);
}

DEV void gload16(const void* g, void* lds) {
  __builtin_amdgcn_global_load_lds((__attribute__((address_space(1))) void*)g,
                                   (__attribute__((address_space(3))) void*)lds,
                                   16, 0, 0);
}

DEV h2 cvtpk(float a, float b) {
  return __builtin_bit_cast(h2, __builtin_amdgcn_cvt_pkrtz(a, b));
}

// ---------------- fp32 -> fp16 conversion (x + packed weights) ----------------
__global__ __launch_bounds__(256) void cvt_all(
    const float* __restrict__ x,  const float* __restrict__ wq,
    const float* __restrict__ wk, const float* __restrict__ wv,
    const float* __restrict__ wo,
    _Float16* __restrict__ xb, _Float16* __restrict__ wqkv, _Float16* __restrict__ wob)
{
  int b = blockIdx.x;
  const float* src; _Float16* dst; int i4;
  if      (b < 8192)  { src = x;  dst = xb;                 i4 = b * 256; }
  else if (b < 9216)  { src = wq; dst = wqkv;               i4 = (b - 8192)  * 256; }
  else if (b < 10240) { src = wk; dst = wqkv + (1u << 20);  i4 = (b - 9216)  * 256; }
  else if (b < 11264) { src = wv; dst = wqkv + (2u << 20);  i4 = (b - 10240) * 256; }
  else                { src = wo; dst = wob;                i4 = (b - 11264) * 256; }
  i4 += threadIdx.x;
  f4 v = ((const f4*)src)[i4];
  h4 o;
  o[0] = (_Float16)v[0]; o[1] = (_Float16)v[1];
  o[2] = (_Float16)v[2]; o[3] = (_Float16)v[3];
  ((h4*)dst)[i4] = o;
}

// -------- GEMM: C[M,N] = A[M,K] * Bt[N,K]^T, tile 256x128, 8 waves ----------
// Triple-buffered BK=32 pipeline, counted vmcnt(3) (never 0 mid-loop), chunk-XOR
// LDS swizzle (T2), setprio around MFMA clusters (T5), XCD-chunked bid swizzle.
// MODE 0: fp32 C row-major (cols = N param).
// MODE 1: scatter fp16 into Q (scaled) / K [B,H,S,HD] or V^T [B,H,HD,S];
//         each block's 128-col range lies in exactly one of Q/K/V.
template<int MODE>
__global__ __launch_bounds__(512) void gemm8(
    const _Float16* __restrict__ A, const _Float16* __restrict__ Bt,
    float* __restrict__ C,
    _Float16* __restrict__ Qo, _Float16* __restrict__ Ko, _Float16* __restrict__ Vo,
    int N, int Nt)
{
  __shared__ _Float16 Al[3][8192];   // [buf][row 256][chunk 4][8], source-swizzled
  __shared__ _Float16 Bl[3][4096];   // [buf][row 128][chunk 4][8]
  const int K = 1024, NT = 32;

  int bid = blockIdx.x;
  int cpx = gridDim.x >> 3;                      // grid % 8 == 0 (bijective)
  bid = (bid & 7) * cpx + (bid >> 3);            // XCD-chunked swizzle
  int tm = bid / Nt, tn = bid - tm * Nt;
  int m0 = tm * 256, n0 = tn * 128;

  int t = threadIdx.x, w = t >> 6, l = t & 63, lo = l & 15, hi = l >> 4;
  int wm = w >> 2, wn = w & 3;

  // staging: thread t covers LDS row rA = t>>2 (linear dest), 16B chunk cA;
  // source chunk pre-swizzled with the same XOR the reads use (involution).
  int rA = t >> 2, cA = t & 3;
  int csw = (cA ^ ((rA >> 1) & 3)) * 8;
  const _Float16* Ag0 = A + (size_t)(m0 + rA) * K + csw;
  const _Float16* Ag1 = Ag0 + (size_t)128 * K;
  const _Float16* Bg  = Bt + (size_t)(n0 + rA) * K + csw;
  _Float16* Ad = &Al[0][0] + w * 512;
  _Float16* Bd = &Bl[0][0] + w * 512;

  // fragment read offsets (chunk ^= (row>>1)&3 == (lo>>1)&3 for all frags)
  int swz = (lo >> 1) & 3;
  int aoff[8], boff[2];
  #pragma unroll
  for (int mi = 0; mi < 8; ++mi)
    aoff[mi] = (wm * 128 + mi * 16 + lo) * 32 + ((hi ^ swz) * 8);
  #pragma unroll
  for (int nf = 0; nf < 2; ++nf)
    boff[nf] = (wn * 32 + nf * 16 + lo) * 32 + ((hi ^ swz) * 8);

  f4 acc[8][2] = {};

#define STAGE_A(buf, kt) do {                                  \
    gload16(Ag0 + (kt) * 32, Ad + (buf) * 8192);               \
    gload16(Ag1 + (kt) * 32, Ad + (buf) * 8192 + 4096);        \
  } while (0)
#define STAGE_B(buf, kt) do {                                  \
    gload16(Bg + (kt) * 32, Bd + (buf) * 4096);                \
  } while (0)

  STAGE_A(0, 0); STAGE_B(0, 0);
  STAGE_A(1, 1); STAGE_B(1, 1);

  int cb = 0;
  for (int kt = 0; kt < NT; ++kt) {
    if (kt + 1 < NT) {
      asm volatile("s_waitcnt vmcnt(3)" ::: "memory");   // tile kt ready; kt+1 in flight
    } else {
      asm volatile("s_waitcnt vmcnt(0)" ::: "memory");   // last tile: drain
    }
    __builtin_amdgcn_sched_barrier(0);
    __builtin_amdgcn_s_barrier();
    __builtin_amdgcn_sched_barrier(0);

    const _Float16* Ac = &Al[0][0] + cb * 8192;
    const _Float16* Bc = &Bl[0][0] + cb * 4096;
    int nb = cb + 2; if (nb >= 3) nb -= 3;               // buffer of tile kt+2

    // ---- phase A: stage A(kt+2), read b0,b1 + a0..a3, 8 MFMA ----
    if (kt + 2 < NT) STAGE_A(nb, kt + 2);
    h8 b0 = *(const h8*)(Bc + boff[0]);
    h8 b1 = *(const h8*)(Bc + boff[1]);
    h8 a0 = *(const h8*)(Ac + aoff[0]);
    h8 a1 = *(const h8*)(Ac + aoff[1]);
    h8 a2 = *(const h8*)(Ac + aoff[2]);
    h8 a3 = *(const h8*)(Ac + aoff[3]);
    __builtin_amdgcn_s_setprio(1);
    acc[0][0] = mfma16(a0, b0, acc[0][0]); acc[0][1] = mfma16(a0, b1, acc[0][1]);
    acc[1][0] = mfma16(a1, b0, acc[1][0]); acc[1][1] = mfma16(a1, b1, acc[1][1]);
    acc[2][0] = mfma16(a2, b0, acc[2][0]); acc[2][1] = mfma16(a2, b1, acc[2][1]);
    acc[3][0] = mfma16(a3, b0, acc[3][0]); acc[3][1] = mfma16(a3, b1, acc[3][1]);
    __builtin_amdgcn_s_setprio(0);
    __builtin_amdgcn_sched_barrier(0);

    // ---- phase B: stage B(kt+2), read a4..a7, 8 MFMA (b reused) ----
    if (kt + 2 < NT) STAGE_B(nb, kt + 2);
    h8 a4 = *(const h8*)(Ac + aoff[4]);
    h8 a5 = *(const h8*)(Ac + aoff[5]);
    h8 a6 = *(const h8*)(Ac + aoff[6]);
    h8 a7 = *(const h8*)(Ac + aoff[7]);
    __builtin_amdgcn_s_setprio(1);
    acc[4][0] = mfma16(a4, b0, acc[4][0]); acc[4][1] = mfma16(a4, b1, acc[4][1]);
    acc[5][0] = mfma16(a5, b0, acc[5][0]); acc[5][1] = mfma16(a5, b1, acc[5][1]);
    acc[6][0] = mfma16(a6, b0, acc[6][0]); acc[6][1] = mfma16(a6, b1, acc[6][1]);
    acc[7][0] = mfma16(a7, b0, acc[7][0]); acc[7][1] = mfma16(a7, b1, acc[7][1]);
    __builtin_amdgcn_s_setprio(0);
    __builtin_amdgcn_sched_barrier(0);

    cb = cb + 1; if (cb == 3) cb = 0;
  }
#undef STAGE_A
#undef STAGE_B

  // ---- epilogue ----
  if (MODE == 0) {
    #pragma unroll
    for (int mi = 0; mi < 8; ++mi)
      #pragma unroll
      for (int nf = 0; nf < 2; ++nf)
        #pragma unroll
        for (int j = 0; j < 4; ++j) {
          int row = m0 + wm * 128 + mi * 16 + hi * 4 + j;
          int col = n0 + wn * 32 + nf * 16 + lo;
          C[(size_t)row * N + col] = acc[mi][nf][j];
        }
  } else {
    int which = n0 >> 10;                       // block-uniform: Q/K/V
    int cb0 = (n0 & 1023) + wn * 32;
    if (which == 2) {                           // V: transposed, j-contiguous h4
      #pragma unroll
      for (int mi = 0; mi < 8; ++mi) {
        int row0 = m0 + wm * 128 + mi * 16 + hi * 4;
        int bb = row0 >> 11, ss0 = row0 & 2047;
        #pragma unroll
        for (int nf = 0; nf < 2; ++nf) {
          int col = cb0 + nf * 16 + lo;
          int hh = col >> 6, hd = col & 63;
          h4 o4;
          o4[0] = (_Float16)acc[mi][nf][0]; o4[1] = (_Float16)acc[mi][nf][1];
          o4[2] = (_Float16)acc[mi][nf][2]; o4[3] = (_Float16)acc[mi][nf][3];
          *(h4*)(Vo + (size_t)(bb * 16 + hh) * 131072 + (size_t)hd * 2048 + ss0) = o4;
        }
      }
    } else {
      _Float16* Dst = (which == 0) ? Qo : Ko;
      float qs = (which == 0) ? 0.1803368801111137f : 1.0f;  // 1/8 * log2(e)
      #pragma unroll
      for (int mi = 0; mi < 8; ++mi)
        #pragma unroll
        for (int nf = 0; nf < 2; ++nf)
          #pragma unroll
          for (int j = 0; j < 4; ++j) {
            int row = m0 + wm * 128 + mi * 16 + hi * 4 + j;
            int col = cb0 + nf * 16 + lo;
            int hh = col >> 6, hd = col & 63;
            int bb = row >> 11, ss = row & 2047;
            Dst[(size_t)(bb * 16 + hh) * 131072 + (size_t)ss * 64 + hd] =
                (_Float16)(acc[mi][nf][j] * qs);
          }
    }
  }
}

// ---------------- causal flash attention, HD=64, S=2048 ----------------------
// grid 1024: bh = bid&63 (XCD = bh%8 -> per-head L2 locality), qi = 15-(bid>>6)
// (longest blocks first). Block = 4 waves x 32 q-rows = QBLK 128; KVBLK=64,
// double-buffered; nkt = 2qi+2 (even) -> kv-loop unrolled x2 with static bufs.
// Swapped QK^T -> in-register softmax with defer-max (THR=8, exp2 domain).
__global__ __launch_bounds__(256, 3) void attn_kernel(
    const _Float16* __restrict__ Q, const _Float16* __restrict__ Kb,
    const _Float16* __restrict__ Vb, _Float16* __restrict__ O)
{
  __shared__ _Float16 Kl[2 * 4096];   // [buf][row 64][chunk^row 8][8]
  __shared__ _Float16 Vl[2 * 4096];   // same, rows = hd (V^T)
  __shared__ _Float16 Pl[4 * 2048];   // per-wave [2 m][16 q][chunk^q 16][4]

  int bid = blockIdx.x;
  int bh = bid & 63, qi = 15 - (bid >> 6);
  int t = threadIdx.x, w = t >> 6, l = t & 63, lo = l & 15, hi = l >> 4;
  const size_t hoff = (size_t)bh * 131072;
  const _Float16* Kg = Kb + hoff;
  const _Float16* Vg = Vb + hoff;     // V^T: [64 hd][2048 s]
  _Float16* Pw = Pl + w * 2048;
  int bb = bh >> 4, hh = bh & 15;
  int swz = (lo & 7) << 1;            // P chunk-XOR (even -> b128-safe)

  // ---- hoisted staging source/dest offsets (elements) ----
  int rs = t >> 3, cs = t & 7;        // rows 0..31 (+32), 16B chunk
  int sw_ = (cs ^ (rs & 7)) * 8;
  int srcK0 = rs * 64 + sw_,   srcK1 = srcK0 + 2048;
  int srcV0 = rs * 2048 + sw_, srcV1 = srcV0 + 65536;
  _Float16* kd0 = Kl + w * 512;
  _Float16* vd0 = Vl + w * 512;

  // ---- hoisted LDS fragment offsets (elements) ----
  int koff[4][2], voff[2][4], pwoff[2][4], proff[2][2];
  #pragma unroll
  for (int kf = 0; kf < 4; ++kf) {
    int row = kf * 16 + lo;
    koff[kf][0] = row * 64 + ((hi       ^ (row & 7)) * 8);
    koff[kf][1] = row * 64 + (((4 + hi) ^ (row & 7)) * 8);
  }
  #pragma unroll
  for (int ks = 0; ks < 2; ++ks)
    #pragma unroll
    for (int df = 0; df < 4; ++df) {
      int row = df * 16 + lo;
      voff[ks][df] = row * 64 + ((((ks << 2) | hi) ^ (row & 7)) * 8);
    }
  #pragma unroll
  for (int m = 0; m < 2; ++m) {
    #pragma unroll
    for (int kf = 0; kf < 4; ++kf)
      pwoff[m][kf] = m * 1024 + lo * 64 + ((((kf << 2) | hi) ^ swz) * 4);
    #pragma unroll
    for (int ks = 0; ks < 2; ++ks)
      proff[m][ks] = m * 1024 + lo * 64 + ((((ks << 3) | (hi << 1)) ^ swz) * 4);
  }

  h8 ones;
  #pragma unroll
  for (int e = 0; e < 8; ++e) ones[e] = (_Float16)1.0f;

  int qb = qi * 128 + w * 32;
  const _Float16* Qp = Q + hoff + (size_t)(qb + lo) * 64 + hi * 8;
  h8 qf[2][2];
  qf[0][0] = *(const h8*)(Qp);
  qf[0][1] = *(const h8*)(Qp + 32);
  qf[1][0] = *(const h8*)(Qp + 1024);
  qf[1][1] = *(const h8*)(Qp + 1056);

  f4 acc[2][4] = {};
  float m_run[2] = {-1e30f, -1e30f};
  float l_run[2] = {0.f, 0.f};
  int nkt = 2 * qi + 2;

#define STAGE(buf, kt) do {                                                   \
    const _Float16* Kt_ = Kg + (size_t)(kt) * 4096;                           \
    const _Float16* Vt_ = Vg + (size_t)(kt) * 64;                             \
    gload16(Kt_ + srcK0, kd0 + (buf) * 4096);                                 \
    gload16(Kt_ + srcK1, kd0 + (buf) * 4096 + 2048);                          \
    gload16(Vt_ + srcV0, vd0 + (buf) * 4096);                                 \
    gload16(Vt_ + srcV1, vd0 + (buf) * 4096 + 2048);                          \
  } while (0)

#define ITER(kt, buf) do {                                                    \
    if ((kt) + 1 < nkt) STAGE(buf ^ 1, (kt) + 1);                             \
    const _Float16* Kc = Kl + (buf) * 4096;                                   \
    const _Float16* Vc = Vl + (buf) * 4096;                                   \
    f4 sc[2][4] = {};                                                         \
    __builtin_amdgcn_s_setprio(1);                                            \
    _Pragma("unroll")                                                         \
    for (int kf = 0; kf < 4; ++kf) {                                          \
      h8 k0 = *(const h8*)(Kc + koff[kf][0]);                                 \
      h8 k1 = *(const h8*)(Kc + koff[kf][1]);                                 \
      _Pragma("unroll")                                                       \
      for (int m = 0; m < 2; ++m) {                                           \
        sc[m][kf] = mfma16(k0, qf[m][0], sc[m][kf]);                          \
        sc[m][kf] = mfma16(k1, qf[m][1], sc[m][kf]);                          \
      }                                                                       \
    }                                                                         \
    __builtin_amdgcn_s_setprio(0);                                            \
    if ((kt) >= 2 * qi) {                                                     \
      _Pragma("unroll")                                                       \
      for (int m = 0; m < 2; ++m) {                                           \
        int qg = qb + m * 16 + lo;                                            \
        _Pragma("unroll")                                                     \
        for (int kf = 0; kf < 4; ++kf) {                                      \
          int kgb = (kt) * 64 + kf * 16 + hi * 4;                             \
          _Pragma("unroll")                                                   \
          for (int j = 0; j < 4; ++j)                                         \
            if (kgb + j > qg) sc[m][kf][j] = -1e30f;                          \
        }                                                                     \
      }                                                                       \
    }                                                                         \
    _Pragma("unroll")                                                         \
    for (int m = 0; m < 2; ++m) {                                             \
      f4 m4 = sc[m][0];                                                       \
      _Pragma("unroll")                                                       \
      for (int kf = 1; kf < 4; ++kf) {                                        \
        m4[0] = fmaxf(m4[0], sc[m][kf][0]); m4[1] = fmaxf(m4[1], sc[m][kf][1]);\
        m4[2] = fmaxf(m4[2], sc[m][kf][2]); m4[3] = fmaxf(m4[3], sc[m][kf][3]);\
      }                                                                       \
      float mx = fmaxf(fmaxf(m4[0], m4[1]), fmaxf(m4[2], m4[3]));             \
      if (!__all(mx <= m_run[m] + 8.f)) {     /* defer-max: rare path */      \
        mx = fmaxf(mx, __shfl_xor(mx, 16));                                   \
        mx = fmaxf(mx, __shfl_xor(mx, 32));                                   \
        float mn = fmaxf(m_run[m], mx);                                       \
        float cr = exp2f(m_run[m] - mn);                                      \
        m_run[m] = mn;                                                        \
        l_run[m] *= cr;                                                       \
        _Pragma("unroll")                                                     \
        for (int df = 0; df < 4; ++df) {                                      \
          acc[m][df][0] *= cr; acc[m][df][1] *= cr;                           \
          acc[m][df][2] *= cr; acc[m][df][3] *= cr;                           \
        }                                                                     \
      }                                                                       \
      float mn = m_run[m];                                                    \
      _Pragma("unroll")                                                       \
      for (int kf = 0; kf < 4; ++kf) {                                        \
        h4 pk;                                                                \
        pk.xy = cvtpk(exp2f(sc[m][kf][0] - mn), exp2f(sc[m][kf][1] - mn));    \
        pk.zw = cvtpk(exp2f(sc[m][kf][2] - mn), exp2f(sc[m][kf][3] - mn));    \
        *(h4*)(Pw + pwoff[m][kf]) = pk;                                       \
      }                                                                       \
    }                                                                         \
    __builtin_amdgcn_sched_barrier(0);                                        \
    asm volatile("s_waitcnt lgkmcnt(0)" ::: "memory");                        \
    __builtin_amdgcn_sched_barrier(0);                                        \
    f4 ls[2] = {};                                                            \
    __builtin_amdgcn_s_setprio(1);                                            \
    _Pragma("unroll")                                                         \
    for (int ks = 0; ks < 2; ++ks) {                                          \
      h8 pf[2];                                                               \
      _Pragma("unroll")                                                       \
      for (int m = 0; m < 2; ++m) {                                           \
        pf[m] = *(const h8*)(Pw + proff[m][ks]);                              \
        ls[m] = mfma16(ones, pf[m], ls[m]);                                   \
      }                                                                       \
      _Pragma("unroll")                                                       \
      for (int df = 0; df < 4; ++df) {                                        \
        h8 vf = *(const h8*)(Vc + voff[ks][df]);                              \
        _Pragma("unroll")                                                     \
        for (int m = 0; m < 2; ++m)                                           \
          acc[m][df] = mfma16(vf, pf[m], acc[m][df]);                         \
      }                                                                       \
    }                                                                         \
    __builtin_amdgcn_s_setprio(0);                                            \
    l_run[0] += ls[0][0];                                                     \
    l_run[1] += ls[1][0];                                                     \
    asm volatile("s_waitcnt vmcnt(0)" ::: "memory");                          \
    __syncthreads();                                                          \
  } while (0)

  STAGE(0, 0);
  asm volatile("s_waitcnt vmcnt(0)" ::: "memory");
  __syncthreads();

  for (int kt = 0; kt < nkt; kt += 2) {
    ITER(kt, 0);
    ITER(kt + 1, 1);
  }

  // epilogue: lane (hi,lo) holds O[q = qb+m*16+lo][d = df*16+hi*4+j]
  #pragma unroll
  for (int m = 0; m < 2; ++m) {
    float inv = 1.0f / l_run[m];
    int q = qb + m * 16 + lo;
    _Float16* Op = O + ((size_t)(bb * 2048 + q)) * 1024 + hh * 64 + (hi << 2);
    #pragma unroll
    for (int df = 0; df < 4; ++df) {
      h4 o4;
      o4[0] = (_Float16)(acc[m][df][0] * inv);
      o4[1] = (_Float16)(acc[m][df][1] * inv);
      o4[2] = (_Float16)(acc[m][df][2] * inv);
      o4[3] = (_Float16)(acc[m][df][3] * inv);
      *(h4*)(Op + df * 16) = o4;
    }
  }
#undef ITER
#undef STAGE
}

extern "C" void kernel_launch(void* const* d_in, const int* in_sizes, int n_in,
                              void* d_out, int out_size, void* d_ws, size_t ws_size,
                              hipStream_t stream)
{
  const float* x  = (const float*)d_in[0];
  const float* wq = (const float*)d_in[1];
  const float* wk = (const float*)d_in[2];
  const float* wv = (const float*)d_in[3];
  const float* wo = (const float*)d_in[4];
  // d_in[5] = causal mask: implemented analytically.

  char* ws = (char*)d_ws;
  _Float16* xb   = (_Float16*)(ws);                  // 16 MB, reused as Ob later
  _Float16* wqkv = (_Float16*)(ws + (16u << 20));    //  6 MB
  _Float16* wob  = (_Float16*)(ws + (22u << 20));    //  2 MB
  _Float16* Qb   = (_Float16*)(ws + (24u << 20));    // 16 MB
  _Float16* Kb   = (_Float16*)(ws + (40u << 20));    // 16 MB
  _Float16* Vb   = (_Float16*)(ws + (56u << 20));    // 16 MB (transposed)
  _Float16* Ob   = xb;                               // xb dead after QKV GEMM

  cvt_all<<<12288, 256, 0, stream>>>(x, wq, wk, wv, wo, xb, wqkv, wob);
  gemm8<1><<<32 * 24, 512, 0, stream>>>(xb, wqkv, nullptr, Qb, Kb, Vb, 3072, 24);
  attn_kernel<<<1024, 256, 0, stream>>>(Qb, Kb, Vb, Ob);
  gemm8<0><<<32 * 8, 512, 0, stream>>>(Ob, wob, (float*)d_out,
                                       nullptr, nullptr, nullptr, 1024, 8);
}

// Round 6
// 166.226 us; speedup vs baseline: 2.0864x; 1.1576x over previous
//
#include <hip/hip_runtime.h>

typedef float    f4 __attribute__((ext_vector_type(4)));
typedef _Float16 h8 __attribute__((ext_vector_type(8)));
typedef _Float16 h4 __attribute__((ext_vector_type(4)));
typedef _Float16 h2 __attribute__((ext_vector_type(2)));

#define DEV static __device__ __forceinline__

DEV f4 mfma16(h8 a, h8 b, f4 c) {
  return __builtin_amdgcn_mfma_f32_16x16x32_f16(a, b, c, 0, 0, 0);
}

DEV void gload16(const void* g, void* lds) {
  __builtin_amdgcn_global_load_lds((__attribute__((address_space(1))) void*)g,
                                   (__attribute__((address_space(3))) void*)lds,
                                   16, 0, 0);
}

DEV h2 cvtpk(float a, float b) {
  return __builtin_bit_cast(h2, __builtin_amdgcn_cvt_pkrtz(a, b));
}

// ---------------- fp32 -> fp16 conversion (x + packed weights) ----------------
__global__ __launch_bounds__(256) void cvt_all(
    const float* __restrict__ x,  const float* __restrict__ wq,
    const float* __restrict__ wk, const float* __restrict__ wv,
    const float* __restrict__ wo,
    _Float16* __restrict__ xb, _Float16* __restrict__ wqkv, _Float16* __restrict__ wob)
{
  int b = blockIdx.x;
  const float* src; _Float16* dst; int i4;
  if      (b < 8192)  { src = x;  dst = xb;                 i4 = b * 256; }
  else if (b < 9216)  { src = wq; dst = wqkv;               i4 = (b - 8192)  * 256; }
  else if (b < 10240) { src = wk; dst = wqkv + (1u << 20);  i4 = (b - 9216)  * 256; }
  else if (b < 11264) { src = wv; dst = wqkv + (2u << 20);  i4 = (b - 10240) * 256; }
  else                { src = wo; dst = wob;                i4 = (b - 11264) * 256; }
  i4 += threadIdx.x;
  f4 v = ((const f4*)src)[i4];
  h4 o;
  o[0] = (_Float16)v[0]; o[1] = (_Float16)v[1];
  o[2] = (_Float16)v[2]; o[3] = (_Float16)v[3];
  ((h4*)dst)[i4] = o;
}

// ======== 8-phase GEMM: C[M,N] = A[M,K] * Bt[N,K]^T, BN=256, BK=64 ==========
// 8 waves (2M x 4N); BM = MF*32 (MF = m-frags/wave = 8 or 4). Double-buffered
// quadrant regions; counted vmcnt (never 0 mid-loop); chunk^row&7 swizzle via
// pre-swizzled global source; setprio around each 16-MFMA cluster.
// MODE 0: fp32 C row-major. MODE 1: Q(scaled)/K [B,H,S,HD], V^T [B,H,HD,S].
template<int MODE, int MF>
__global__ __launch_bounds__(512) void gemmT(
    const _Float16* __restrict__ A, const _Float16* __restrict__ Bt,
    float* __restrict__ C,
    _Float16* __restrict__ Qo, _Float16* __restrict__ Ko, _Float16* __restrict__ Vo,
    int N, int Nt)
{
  constexpr int ASZ = MF * 16 * 64;   // A quadrant region (f16): 2 wm-panels
  constexpr int BSZ = 8192;           // B quadrant region: 4 wn-panels x 32 x 64
  constexpr int V1  = (MF == 8) ? 12 : 9;   // steady vmcnt @P1/P3/P5/P7
  constexpr int V2  = (MF == 8) ? 10 : 7;   // steady vmcnt @P2/P6
  constexpr int VL3 = (MF == 8) ? 8 : 6;    // last-iter drains
  constexpr int VL5 = (MF == 8) ? 4 : 3;
  constexpr int VL6 = (MF == 8) ? 2 : 1;
  __shared__ _Float16 Al[4 * ASZ];    // [buf][q]
  __shared__ _Float16 Bl[4 * BSZ];    // [buf][qn]

  int bid = blockIdx.x;
  int cpx = gridDim.x >> 3;                  // grid % 8 == 0 (bijective)
  bid = (bid & 7) * cpx + (bid >> 3);        // XCD-chunked swizzle
  int tm = bid / Nt, tn = bid - tm * Nt;
  int m0 = tm * (MF * 32), n0 = tn * 256;

  int t = threadIdx.x, w = t >> 6, l = t & 63, lo = l & 15, hi = l >> 4;
  int wm = w >> 2, wn = w & 3;

  // ---- staging sources (pre-swizzled chunk: involution chunk^=(row&7)) ----
  int rsc = t >> 3;                          // 0..63
  int csrc = ((t & 7) ^ (rsc & 7)) * 8;
  const _Float16 *As[2][2], *Bs[2][2];
  #pragma unroll
  for (int q = 0; q < 2; ++q) {
    if (MF == 8) {
      As[q][0] = A + (size_t)(m0 + q * 64 + rsc) * 1024 + csrc;
      As[q][1] = A + (size_t)(m0 + 128 + q * 64 + rsc) * 1024 + csrc;
    } else {
      As[q][0] = A + (size_t)(m0 + (t >> 8) * 64 + q * 32 + (rsc & 31)) * 1024 + csrc;
      As[q][1] = As[q][0];
    }
    #pragma unroll
    for (int h = 0; h < 2; ++h)
      Bs[q][h] = Bt + (size_t)(n0 + (2 * h + (t >> 8)) * 64 + q * 32 + (rsc & 31)) * 1024 + csrc;
  }
  _Float16* Adst = Al + w * 512;
  _Float16* Bdst = Bl + w * 512;

  // ---- fragment read offsets (f16 units) ----
  int awoff = wm * (MF * 8 * 64) + lo * 64;
  int bwoff = wn * 2048 + lo * 64;
  int s0 = (hi ^ (lo & 7)) * 8;
  int s1 = ((4 + hi) ^ (lo & 7)) * 8;

  f4 acc[MF][4] = {};
  h8 ar[MF / 2][2], br[2][2][2];

#define VMW(n)  asm volatile("s_waitcnt vmcnt(%0)" :: "n"(n) : "memory")
#define BARR    __builtin_amdgcn_s_barrier()
#define LGKM0   do { asm volatile("s_waitcnt lgkmcnt(0)" ::: "memory"); \
                     __builtin_amdgcn_sched_barrier(0); } while (0)
#define STA(BUF, Q, KO) do { \
    gload16(As[Q][0] + (KO), Adst + ((BUF) * 2 + (Q)) * ASZ); \
    if (MF == 8) gload16(As[Q][1] + (KO), Adst + ((BUF) * 2 + (Q)) * ASZ + 4096); \
  } while (0)
#define STB(BUF, QN, KO) do { \
    gload16(Bs[QN][0] + (KO), Bdst + ((BUF) * 2 + (QN)) * BSZ); \
    gload16(Bs[QN][1] + (KO), Bdst + ((BUF) * 2 + (QN)) * BSZ + 4096); \
  } while (0)
#define RDA(BUF, Q) do { \
    const _Float16* p_ = Al + ((BUF) * 2 + (Q)) * ASZ + awoff; \
    _Pragma("unroll") \
    for (int f_ = 0; f_ < MF / 2; ++f_) { \
      ar[f_][0] = *(const h8*)(p_ + f_ * 1024 + s0); \
      ar[f_][1] = *(const h8*)(p_ + f_ * 1024 + s1); } \
  } while (0)
#define RDB(BUF, QN, D) do { \
    const _Float16* p_ = Bl + ((BUF) * 2 + (QN)) * BSZ + bwoff; \
    br[D][0][0] = *(const h8*)(p_ + s0);        br[D][0][1] = *(const h8*)(p_ + s1); \
    br[D][1][0] = *(const h8*)(p_ + 1024 + s0); br[D][1][1] = *(const h8*)(p_ + 1024 + s1); \
  } while (0)
#define MM(MH, D) do { \
    __builtin_amdgcn_s_setprio(1); \
    _Pragma("unroll") \
    for (int f_ = 0; f_ < MF / 2; ++f_) \
      _Pragma("unroll") \
      for (int g_ = 0; g_ < 2; ++g_) { \
        acc[(MH) * (MF / 2) + f_][(D) * 2 + g_] = \
            mfma16(ar[f_][0], br[D][g_][0], acc[(MH) * (MF / 2) + f_][(D) * 2 + g_]); \
        acc[(MH) * (MF / 2) + f_][(D) * 2 + g_] = \
            mfma16(ar[f_][1], br[D][g_][1], acc[(MH) * (MF / 2) + f_][(D) * 2 + g_]); } \
    __builtin_amdgcn_s_setprio(0); \
    __builtin_amdgcn_sched_barrier(0); \
  } while (0)

  // prologue: tiles 0 (buf0) and 1 (buf1), region order Aq0,Bq0 | Bq1 | Aq1
  STA(0, 0, 0);  STB(0, 0, 0);  STB(0, 1, 0);  STA(0, 1, 0);
  STA(1, 0, 64); STB(1, 0, 64); STB(1, 1, 64); STA(1, 1, 64);

  int kof = 128;                         // element offset of tile 2it+2
  #pragma unroll 1
  for (int it = 0; it < 7; ++it) {       // NT/2 - 1 steady iterations
    VMW(V1); BARR; RDA(0, 0); RDB(0, 0, 0); LGKM0; MM(0, 0);
    VMW(V2); BARR; RDB(0, 1, 1); STA(0, 0, kof); STB(0, 0, kof); LGKM0; MM(0, 1);
    VMW(V1); BARR; RDA(0, 1); STB(0, 1, kof); LGKM0; MM(1, 1);
    BARR; STA(0, 1, kof); MM(1, 0);
    VMW(V1); BARR; RDA(1, 0); RDB(1, 0, 0); LGKM0; MM(0, 0);
    VMW(V2); BARR; RDB(1, 1, 1); STA(1, 0, kof + 64); STB(1, 0, kof + 64); LGKM0; MM(0, 1);
    VMW(V1); BARR; RDA(1, 1); STB(1, 1, kof + 64); LGKM0; MM(1, 1);
    BARR; STA(1, 1, kof + 64); MM(1, 0);
    kof += 128;
  }
  // last iteration: no staging, drain counts
  VMW(V1);  BARR; RDA(0, 0); RDB(0, 0, 0); LGKM0; MM(0, 0);
  VMW(V2);  BARR; RDB(0, 1, 1); LGKM0; MM(0, 1);
  VMW(VL3); BARR; RDA(0, 1); LGKM0; MM(1, 1);
  BARR; MM(1, 0);
  VMW(VL5); BARR; RDA(1, 0); RDB(1, 0, 0); LGKM0; MM(0, 0);
  VMW(VL6); BARR; RDB(1, 1, 1); LGKM0; MM(0, 1);
  VMW(0);   BARR; RDA(1, 1); LGKM0; MM(1, 1);
  BARR; MM(1, 0);

#undef VMW
#undef BARR
#undef LGKM0
#undef STA
#undef STB
#undef RDA
#undef RDB
#undef MM

  // ---- epilogue ----
  if (MODE == 0) {
    #pragma unroll
    for (int mi = 0; mi < MF; ++mi)
      #pragma unroll
      for (int nf = 0; nf < 4; ++nf)
        #pragma unroll
        for (int j = 0; j < 4; ++j) {
          int row = m0 + wm * (MF * 16) + mi * 16 + hi * 4 + j;
          int col = n0 + wn * 64 + nf * 16 + lo;
          C[(size_t)row * N + col] = acc[mi][nf][j];
        }
  } else {
    int which = n0 >> 10;                     // block-uniform (1024 % 256 == 0)
    int cb0 = (n0 & 1023) + wn * 64;
    if (which == 2) {                         // V: transposed, j-contiguous h4
      #pragma unroll
      for (int mi = 0; mi < MF; ++mi) {
        int row0 = m0 + wm * (MF * 16) + mi * 16 + hi * 4;
        int bb = row0 >> 11, ss0 = row0 & 2047;
        #pragma unroll
        for (int nf = 0; nf < 4; ++nf) {
          int col = cb0 + nf * 16 + lo;
          int hh = col >> 6, hd = col & 63;
          h4 o4;
          o4[0] = (_Float16)acc[mi][nf][0]; o4[1] = (_Float16)acc[mi][nf][1];
          o4[2] = (_Float16)acc[mi][nf][2]; o4[3] = (_Float16)acc[mi][nf][3];
          *(h4*)(Vo + (size_t)(bb * 16 + hh) * 131072 + (size_t)hd * 2048 + ss0) = o4;
        }
      }
    } else {
      _Float16* Dst = (which == 0) ? Qo : Ko;
      float qs = (which == 0) ? 0.1803368801111137f : 1.0f;   // 1/8 * log2(e)
      #pragma unroll
      for (int mi = 0; mi < MF; ++mi)
        #pragma unroll
        for (int nf = 0; nf < 4; ++nf)
          #pragma unroll
          for (int j = 0; j < 4; ++j) {
            int row = m0 + wm * (MF * 16) + mi * 16 + hi * 4 + j;
            int col = cb0 + nf * 16 + lo;
            int hh = col >> 6, hd = col & 63;
            int bb = row >> 11, ss = row & 2047;
            Dst[(size_t)(bb * 16 + hh) * 131072 + (size_t)ss * 64 + hd] =
                (_Float16)(acc[mi][nf][j] * qs);
          }
    }
  }
}

// ---------------- causal flash attention, HD=64, S=2048 ----------------------
// grid 1024: bh = bid&63 (XCD = bh%8 -> per-head L2 locality), qi = 15-(bid>>6)
// (longest blocks first). Block = 4 waves x 32 q-rows = QBLK 128; KVBLK=64,
// double-buffered; nkt = 2qi+2 (even) -> kv-loop unrolled x2 with static bufs.
// Swapped QK^T -> in-register softmax with defer-max (THR=8, exp2 domain).
__global__ __launch_bounds__(256, 3) void attn_kernel(
    const _Float16* __restrict__ Q, const _Float16* __restrict__ Kb,
    const _Float16* __restrict__ Vb, _Float16* __restrict__ O)
{
  __shared__ _Float16 Kl[2 * 4096];   // [buf][row 64][chunk^row 8][8]
  __shared__ _Float16 Vl[2 * 4096];   // same, rows = hd (V^T)
  __shared__ _Float16 Pl[4 * 2048];   // per-wave [2 m][16 q][chunk^q 16][4]

  int bid = blockIdx.x;
  int bh = bid & 63, qi = 15 - (bid >> 6);
  int t = threadIdx.x, w = t >> 6, l = t & 63, lo = l & 15, hi = l >> 4;
  const size_t hoff = (size_t)bh * 131072;
  const _Float16* Kg = Kb + hoff;
  const _Float16* Vg = Vb + hoff;     // V^T: [64 hd][2048 s]
  _Float16* Pw = Pl + w * 2048;
  int bb = bh >> 4, hh = bh & 15;
  int swz = (lo & 7) << 1;            // P chunk-XOR (even -> b128-safe)

  // ---- hoisted staging source/dest offsets (elements) ----
  int rs = t >> 3, cs = t & 7;        // rows 0..31 (+32), 16B chunk
  int sw_ = (cs ^ (rs & 7)) * 8;
  int srcK0 = rs * 64 + sw_,   srcK1 = srcK0 + 2048;
  int srcV0 = rs * 2048 + sw_, srcV1 = srcV0 + 65536;
  _Float16* kd0 = Kl + w * 512;
  _Float16* vd0 = Vl + w * 512;

  // ---- hoisted LDS fragment offsets (elements) ----
  int koff[4][2], voff[2][4], pwoff[2][4], proff[2][2];
  #pragma unroll
  for (int kf = 0; kf < 4; ++kf) {
    int row = kf * 16 + lo;
    koff[kf][0] = row * 64 + ((hi       ^ (row & 7)) * 8);
    koff[kf][1] = row * 64 + (((4 + hi) ^ (row & 7)) * 8);
  }
  #pragma unroll
  for (int ks = 0; ks < 2; ++ks)
    #pragma unroll
    for (int df = 0; df < 4; ++df) {
      int row = df * 16 + lo;
      voff[ks][df] = row * 64 + ((((ks << 2) | hi) ^ (row & 7)) * 8);
    }
  #pragma unroll
  for (int m = 0; m < 2; ++m) {
    #pragma unroll
    for (int kf = 0; kf < 4; ++kf)
      pwoff[m][kf] = m * 1024 + lo * 64 + ((((kf << 2) | hi) ^ swz) * 4);
    #pragma unroll
    for (int ks = 0; ks < 2; ++ks)
      proff[m][ks] = m * 1024 + lo * 64 + ((((ks << 3) | (hi << 1)) ^ swz) * 4);
  }

  h8 ones;
  #pragma unroll
  for (int e = 0; e < 8; ++e) ones[e] = (_Float16)1.0f;

  int qb = qi * 128 + w * 32;
  const _Float16* Qp = Q + hoff + (size_t)(qb + lo) * 64 + hi * 8;
  h8 qf[2][2];
  qf[0][0] = *(const h8*)(Qp);
  qf[0][1] = *(const h8*)(Qp + 32);
  qf[1][0] = *(const h8*)(Qp + 1024);
  qf[1][1] = *(const h8*)(Qp + 1056);

  f4 acc[2][4] = {};
  float m_run[2] = {-1e30f, -1e30f};
  float l_run[2] = {0.f, 0.f};
  int nkt = 2 * qi + 2;

#define STAGE(buf, kt) do {                                                   \
    const _Float16* Kt_ = Kg + (size_t)(kt) * 4096;                           \
    const _Float16* Vt_ = Vg + (size_t)(kt) * 64;                             \
    gload16(Kt_ + srcK0, kd0 + (buf) * 4096);                                 \
    gload16(Kt_ + srcK1, kd0 + (buf) * 4096 + 2048);                          \
    gload16(Vt_ + srcV0, vd0 + (buf) * 4096);                                 \
    gload16(Vt_ + srcV1, vd0 + (buf) * 4096 + 2048);                          \
  } while (0)

#define ITER(kt, buf) do {                                                    \
    if ((kt) + 1 < nkt) STAGE(buf ^ 1, (kt) + 1);                             \
    const _Float16* Kc = Kl + (buf) * 4096;                                   \
    const _Float16* Vc = Vl + (buf) * 4096;                                   \
    f4 sc[2][4] = {};                                                         \
    __builtin_amdgcn_s_setprio(1);                                            \
    _Pragma("unroll")                                                         \
    for (int kf = 0; kf < 4; ++kf) {                                          \
      h8 k0 = *(const h8*)(Kc + koff[kf][0]);                                 \
      h8 k1 = *(const h8*)(Kc + koff[kf][1]);                                 \
      _Pragma("unroll")                                                       \
      for (int m = 0; m < 2; ++m) {                                           \
        sc[m][kf] = mfma16(k0, qf[m][0], sc[m][kf]);                          \
        sc[m][kf] = mfma16(k1, qf[m][1], sc[m][kf]);                          \
      }                                                                       \
    }                                                                         \
    __builtin_amdgcn_s_setprio(0);                                            \
    if ((kt) >= 2 * qi) {                                                     \
      _Pragma("unroll")                                                       \
      for (int m = 0; m < 2; ++m) {                                           \
        int qg = qb + m * 16 + lo;                                            \
        _Pragma("unroll")                                                     \
        for (int kf = 0; kf < 4; ++kf) {                                      \
          int kgb = (kt) * 64 + kf * 16 + hi * 4;                             \
          _Pragma("unroll")                                                   \
          for (int j = 0; j < 4; ++j)                                         \
            if (kgb + j > qg) sc[m][kf][j] = -1e30f;                          \
        }                                                                     \
      }                                                                       \
    }                                                                         \
    _Pragma("unroll")                                                         \
    for (int m = 0; m < 2; ++m) {                                             \
      f4 m4 = sc[m][0];                                                       \
      _Pragma("unroll")                                                       \
      for (int kf = 1; kf < 4; ++kf) {                                        \
        m4[0] = fmaxf(m4[0], sc[m][kf][0]); m4[1] = fmaxf(m4[1], sc[m][kf][1]);\
        m4[2] = fmaxf(m4[2], sc[m][kf][2]); m4[3] = fmaxf(m4[3], sc[m][kf][3]);\
      }                                                                       \
      float mx = fmaxf(fmaxf(m4[0], m4[1]), fmaxf(m4[2], m4[3]));             \
      if (!__all(mx <= m_run[m] + 8.f)) {     /* defer-max: rare path */      \
        mx = fmaxf(mx, __shfl_xor(mx, 16));                                   \
        mx = fmaxf(mx, __shfl_xor(mx, 32));                                   \
        float mn = fmaxf(m_run[m], mx);                                       \
        float cr = exp2f(m_run[m] - mn);                                      \
        m_run[m] = mn;                                                        \
        l_run[m] *= cr;                                                       \
        _Pragma("unroll")                                                     \
        for (int df = 0; df < 4; ++df) {                                      \
          acc[m][df][0] *= cr; acc[m][df][1] *= cr;                           \
          acc[m][df][2] *= cr; acc[m][df][3] *= cr;                           \
        }                                                                     \
      }                                                                       \
      float mn = m_run[m];                                                    \
      _Pragma("unroll")                                                       \
      for (int kf = 0; kf < 4; ++kf) {                                        \
        h4 pk;                                                                \
        pk.xy = cvtpk(exp2f(sc[m][kf][0] - mn), exp2f(sc[m][kf][1] - mn));    \
        pk.zw = cvtpk(exp2f(sc[m][kf][2] - mn), exp2f(sc[m][kf][3] - mn));    \
        *(h4*)(Pw + pwoff[m][kf]) = pk;                                       \
      }                                                                       \
    }                                                                         \
    __builtin_amdgcn_sched_barrier(0);                                        \
    asm volatile("s_waitcnt lgkmcnt(0)" ::: "memory");                        \
    __builtin_amdgcn_sched_barrier(0);                                        \
    f4 ls[2] = {};                                                            \
    __builtin_amdgcn_s_setprio(1);                                            \
    _Pragma("unroll")                                                         \
    for (int ks = 0; ks < 2; ++ks) {                                          \
      h8 pf[2];                                                               \
      _Pragma("unroll")                                                       \
      for (int m = 0; m < 2; ++m) {                                           \
        pf[m] = *(const h8*)(Pw + proff[m][ks]);                              \
        ls[m] = mfma16(ones, pf[m], ls[m]);                                   \
      }                                                                       \
      _Pragma("unroll")                                                       \
      for (int df = 0; df < 4; ++df) {                                        \
        h8 vf = *(const h8*)(Vc + voff[ks][df]);                              \
        _Pragma("unroll")                                                     \
        for (int m = 0; m < 2; ++m)                                           \
          acc[m][df] = mfma16(vf, pf[m], acc[m][df]);                         \
      }                                                                       \
    }                                                                         \
    __builtin_amdgcn_s_setprio(0);                                            \
    l_run[0] += ls[0][0];                                                     \
    l_run[1] += ls[1][0];                                                     \
    asm volatile("s_waitcnt vmcnt(0)" ::: "memory");                          \
    __syncthreads();                                                          \
  } while (0)

  STAGE(0, 0);
  asm volatile("s_waitcnt vmcnt(0)" ::: "memory");
  __syncthreads();

  for (int kt = 0; kt < nkt; kt += 2) {
    ITER(kt, 0);
    ITER(kt + 1, 1);
  }

  // epilogue: lane (hi,lo) holds O[q = qb+m*16+lo][d = df*16+hi*4+j]
  #pragma unroll
  for (int m = 0; m < 2; ++m) {
    float inv = 1.0f / l_run[m];
    int q = qb + m * 16 + lo;
    _Float16* Op = O + ((size_t)(bb * 2048 + q)) * 1024 + hh * 64 + (hi << 2);
    #pragma unroll
    for (int df = 0; df < 4; ++df) {
      h4 o4;
      o4[0] = (_Float16)(acc[m][df][0] * inv);
      o4[1] = (_Float16)(acc[m][df][1] * inv);
      o4[2] = (_Float16)(acc[m][df][2] * inv);
      o4[3] = (_Float16)(acc[m][df][3] * inv);
      *(h4*)(Op + df * 16) = o4;
    }
  }
#undef ITER
#undef STAGE
}

extern "C" void kernel_launch(void* const* d_in, const int* in_sizes, int n_in,
                              void* d_out, int out_size, void* d_ws, size_t ws_size,
                              hipStream_t stream)
{
  const float* x  = (const float*)d_in[0];
  const float* wq = (const float*)d_in[1];
  const float* wk = (const float*)d_in[2];
  const float* wv = (const float*)d_in[3];
  const float* wo = (const float*)d_in[4];
  // d_in[5] = causal mask: implemented analytically.

  char* ws = (char*)d_ws;
  _Float16* xb   = (_Float16*)(ws);                  // 16 MB, reused as Ob later
  _Float16* wqkv = (_Float16*)(ws + (16u << 20));    //  6 MB
  _Float16* wob  = (_Float16*)(ws + (22u << 20));    //  2 MB
  _Float16* Qb   = (_Float16*)(ws + (24u << 20));    // 16 MB
  _Float16* Kb   = (_Float16*)(ws + (40u << 20));    // 16 MB
  _Float16* Vb   = (_Float16*)(ws + (56u << 20));    // 16 MB (transposed)
  _Float16* Ob   = xb;                               // xb dead after QKV GEMM

  cvt_all<<<12288, 256, 0, stream>>>(x, wq, wk, wv, wo, xb, wqkv, wob);
  gemmT<1, 8><<<32 * 12, 512, 0, stream>>>(xb, wqkv, nullptr, Qb, Kb, Vb, 3072, 12);
  attn_kernel<<<1024, 256, 0, stream>>>(Qb, Kb, Vb, Ob);
  gemmT<0, 4><<<64 * 4, 512, 0, stream>>>(Ob, wob, (float*)d_out,
                                          nullptr, nullptr, nullptr, 1024, 4);
}